// Round 7
// baseline (148.133 us; speedup 1.0000x reference)
//
#include <hip/hip_runtime.h>
#include <hip/hip_bf16.h>
#include <math.h>

#define BB 4
#define NN 4096
#define CC 384
#define NHH 6
#define HDD 64
#define NKK 1024
#define LN_EPS 1e-5f

typedef _Float16 half8 __attribute__((ext_vector_type(8)));
typedef _Float16 half4v __attribute__((ext_vector_type(4)));
typedef _Float16 half2v __attribute__((ext_vector_type(2)));
typedef float f32x4 __attribute__((ext_vector_type(4)));

#define MFMA16(a, b, c) __builtin_amdgcn_mfma_f32_16x16x32_f16((a), (b), (c), 0, 0, 0)

#define GLL16(src, dst)                                                       \
    __builtin_amdgcn_global_load_lds(                                         \
        (const __attribute__((address_space(1))) void*)(src),                 \
        (__attribute__((address_space(3))) void*)(dst), 16, 0, 0)

// ---------------------------------------------------------------------------
// Weight pre-split: Wq,Wk,Wv -> f16 hi/lo pairs; Wp -> f16.
// ---------------------------------------------------------------------------
__global__ __launch_bounds__(256)
void split_w(const float* __restrict__ Wq, const float* __restrict__ Wk,
             const float* __restrict__ Wv, const float* __restrict__ Wp,
             _Float16* __restrict__ qh, _Float16* __restrict__ ql,
             _Float16* __restrict__ kh, _Float16* __restrict__ kl,
             _Float16* __restrict__ vh, _Float16* __restrict__ vl,
             _Float16* __restrict__ ph) {
    int i = blockIdx.x * 256 + threadIdx.x;   // 384*384 = 147456
    float q = Wq[i], k = Wk[i], v = Wv[i], p = Wp[i];
    _Float16 h;
    h = (_Float16)q; qh[i] = h; ql[i] = (_Float16)((q - (float)h) * 256.0f);
    h = (_Float16)k; kh[i] = h; kl[i] = (_Float16)((k - (float)h) * 256.0f);
    h = (_Float16)v; vh[i] = h; vl[i] = (_Float16)((v - (float)h) * 256.0f);
    ph[i] = (_Float16)p;
}

// ---------------------------------------------------------------------------
// Split-f16 MFMA GEMM (unchanged):
// Y = (A(MxK) @ W(NxK)^T + bias) * scale, K=N=384.
// AIN: 0 = f32 A (split on stage), 1 = pre-split f16 pair, 2 = f16 single
// WIN: 1 = pre-split f16 pair, 2 = f16 single
// OUT: 0 = f16 pair, 1 = f16 transposed Vt[b][c][nk], 2 = f32
// ---------------------------------------------------------------------------
template<int AIN, int WIN, int OUT>
__global__ __launch_bounds__(256) void gemm_mf(
    const void* __restrict__ A0, const void* __restrict__ A1,
    const _Float16* __restrict__ Whi, const _Float16* __restrict__ Wlo,
    const float* __restrict__ bias, _Float16* __restrict__ Yhi,
    _Float16* __restrict__ Ylo, float* __restrict__ Yf, float scale)
{
    constexpr bool SPLIT = (AIN != 2);
    __shared__ _Float16 AhiS[128 * 64];
    __shared__ _Float16 AloS[SPLIT ? 128 * 64 : 64];
    __shared__ _Float16 WhiS[64 * 64];
    __shared__ _Float16 WloS[(WIN == 1) ? 64 * 64 : 64];

    const int tid = threadIdx.x;
    const int bm = blockIdx.x * 128;
    const int bn = blockIdx.y * 64;
    const int w = tid >> 6, lane = tid & 63;
    const int g = lane >> 4, n15 = lane & 15;

    f32x4 zero4 = {0.f, 0.f, 0.f, 0.f};
    f32x4 acc_hi[2][4], acc_lo[SPLIT ? 2 : 1][SPLIT ? 4 : 1];
#pragma unroll
    for (int mf = 0; mf < 2; ++mf)
#pragma unroll
        for (int nt = 0; nt < 4; ++nt) {
            acc_hi[mf][nt] = zero4;
            if (SPLIT) acc_lo[mf][nt] = zero4;
        }

    for (int k0 = 0; k0 < CC; k0 += 64) {
        __syncthreads();
        if (AIN == 0) {
            const float* A = (const float*)A0;
#pragma unroll
            for (int i = 0; i < 8; ++i) {
                int id = tid + 256 * i;
                int row = id >> 4, c4 = (id & 15) * 4;
                float4 av = *reinterpret_cast<const float4*>(A + (size_t)(bm + row) * CC + k0 + c4);
                int el = row * 64 + (((c4 >> 3) ^ (row & 7)) * 8) + (c4 & 7);
                float vv[4] = {av.x, av.y, av.z, av.w};
                half4v hi, lo;
#pragma unroll
                for (int e = 0; e < 4; ++e) {
                    _Float16 h = (_Float16)vv[e];
                    hi[e] = h;
                    lo[e] = (_Float16)((vv[e] - (float)h) * 256.0f);
                }
                *reinterpret_cast<half4v*>(&AhiS[el]) = hi;
                *reinterpret_cast<half4v*>(&AloS[el]) = lo;
            }
        } else if (AIN == 1) {
            const _Float16* Ah = (const _Float16*)A0;
            const _Float16* Al = (const _Float16*)A1;
#pragma unroll
            for (int i = 0; i < 4; ++i) {
                int id = tid + 256 * i;
                int row = id >> 3, dg = id & 7;
                size_t go = (size_t)(bm + row) * CC + k0 + dg * 8;
                half8 hv = *reinterpret_cast<const half8*>(Ah + go);
                half8 lv = *reinterpret_cast<const half8*>(Al + go);
                int el = row * 64 + ((dg ^ (row & 7)) * 8);
                *reinterpret_cast<half8*>(&AhiS[el]) = hv;
                *reinterpret_cast<half8*>(&AloS[el]) = lv;
            }
        } else {
            const _Float16* A = (const _Float16*)A0;
#pragma unroll
            for (int i = 0; i < 4; ++i) {
                int id = tid + 256 * i;
                int row = id >> 3, dg = id & 7;
                half8 av = *reinterpret_cast<const half8*>(A + (size_t)(bm + row) * CC + k0 + dg * 8);
                int el = row * 64 + ((dg ^ (row & 7)) * 8);
                *reinterpret_cast<half8*>(&AhiS[el]) = av;
            }
        }
#pragma unroll
        for (int i = 0; i < 2; ++i) {
            int id = tid + 256 * i;
            int row = id >> 3, dg = id & 7;
            size_t go = (size_t)(bn + row) * CC + k0 + dg * 8;
            half8 wh = *reinterpret_cast<const half8*>(Whi + go);
            int el = row * 64 + ((dg ^ (row & 7)) * 8);
            *reinterpret_cast<half8*>(&WhiS[el]) = wh;
            if (WIN == 1) {
                half8 wl = *reinterpret_cast<const half8*>(Wlo + go);
                *reinterpret_cast<half8*>(&WloS[el]) = wl;
            }
        }
        __syncthreads();
#pragma unroll
        for (int kc = 0; kc < 2; ++kc) {
            const int blk = kc * 4 + g;
            half8 a_hi[2], a_lo[2], b_hi[4], b_lo[4];
#pragma unroll
            for (int mf = 0; mf < 2; ++mf) {
                int row = w * 32 + mf * 16 + n15;
                int el = row * 64 + ((blk ^ (row & 7)) * 8);
                a_hi[mf] = *reinterpret_cast<const half8*>(&AhiS[el]);
                if (SPLIT) a_lo[mf] = *reinterpret_cast<const half8*>(&AloS[el]);
            }
#pragma unroll
            for (int nt = 0; nt < 4; ++nt) {
                int row = nt * 16 + n15;
                int el = row * 64 + ((blk ^ (row & 7)) * 8);
                b_hi[nt] = *reinterpret_cast<const half8*>(&WhiS[el]);
                if (WIN == 1) b_lo[nt] = *reinterpret_cast<const half8*>(&WloS[el]);
            }
#pragma unroll
            for (int mf = 0; mf < 2; ++mf)
#pragma unroll
                for (int nt = 0; nt < 4; ++nt) {
                    acc_hi[mf][nt] = MFMA16(a_hi[mf], b_hi[nt], acc_hi[mf][nt]);
                    if (SPLIT) {
                        acc_lo[mf][nt] = MFMA16(a_hi[mf], b_lo[nt], acc_lo[mf][nt]);
                        acc_lo[mf][nt] = MFMA16(a_lo[mf], b_hi[nt], acc_lo[mf][nt]);
                    }
                }
        }
    }
#pragma unroll
    for (int nt = 0; nt < 4; ++nt) {
        int col = bn + nt * 16 + n15;
        float bc = bias[col];
#pragma unroll
        for (int mf = 0; mf < 2; ++mf)
#pragma unroll
            for (int r = 0; r < 4; ++r) {
                size_t row = bm + w * 32 + mf * 16 + g * 4 + r;
                float y = acc_hi[mf][nt][r];
                if (SPLIT) y += acc_lo[mf][nt][r] * (1.0f / 256.0f);
                y = (y + bc) * scale;
                if (OUT == 0) {
                    _Float16 h = (_Float16)y;
                    Yhi[row * CC + col] = h;
                    Ylo[row * CC + col] = (_Float16)((y - (float)h) * 256.0f);
                } else if (OUT == 1) {
                    Yhi[((row >> 10) * CC + col) * NKK + (row & 1023)] = (_Float16)y;
                } else {
                    Yf[row * CC + col] = y;
                }
            }
    }
}

// ---------------------------------------------------------------------------
// Depthwise 2x2 stride-2 conv (VALID) + LayerNorm; writes f16 hi/lo pair.
// ---------------------------------------------------------------------------
__global__ __launch_bounds__(128)
void srconv_ln(const float* __restrict__ x, const float* __restrict__ srw,
               const float* __restrict__ srb, const float* __restrict__ g,
               const float* __restrict__ beta,
               _Float16* __restrict__ xrh, _Float16* __restrict__ xrl) {
    const int row = blockIdx.x;
    const int b  = row >> 10;
    const int nk = row & 1023;
    const int oy = nk >> 5;
    const int ox = nk & 31;
    const int n0 = (2 * oy) * 64 + 2 * ox;
    const float* xb = x + ((size_t)b * NN + n0) * CC;
    const int tid = threadIdx.x;

    float vals[3];
    float lsum = 0.f, lsum2 = 0.f;
#pragma unroll
    for (int i = 0; i < 3; ++i) {
        const int c = tid + i * 128;
        const float4 w = *reinterpret_cast<const float4*>(srw + (size_t)c * 4);
        float v = xb[c] * w.x + xb[CC + c] * w.y +
                  xb[(size_t)64 * CC + c] * w.z + xb[(size_t)65 * CC + c] * w.w + srb[c];
        vals[i] = v;
        lsum += v;
        lsum2 += v * v;
    }
#pragma unroll
    for (int off = 32; off; off >>= 1) {
        lsum  += __shfl_down(lsum, off);
        lsum2 += __shfl_down(lsum2, off);
    }
    __shared__ float ssum[2], ssum2[2];
    if ((tid & 63) == 0) { ssum[tid >> 6] = lsum; ssum2[tid >> 6] = lsum2; }
    __syncthreads();
    const float tot  = ssum[0] + ssum[1];
    const float tot2 = ssum2[0] + ssum2[1];
    const float mu  = tot * (1.0f / 384.0f);
    const float var = tot2 * (1.0f / 384.0f) - mu * mu;
    const float rstd = 1.0f / sqrtf(var + LN_EPS);

    _Float16* oh = xrh + (size_t)row * CC;
    _Float16* ol = xrl + (size_t)row * CC;
#pragma unroll
    for (int i = 0; i < 3; ++i) {
        const int c = tid + i * 128;
        float v = (vals[i] - mu) * rstd * g[c] + beta[c];
        _Float16 h = (_Float16)v;
        oh[c] = h;
        ol[c] = (_Float16)((v - (float)h) * 256.0f);
    }
}

// ---------------------------------------------------------------------------
// Fused MFMA attention, neg-softmax, m == 0 (linear accumulation).
// 256 thr / 4 waves; wave owns 64 q rows (4 x 16-row frags), QT=256/block.
// Shared K-hi/K-lo LDS reads feed 12 MFMAs each (4 frags x 3 split terms);
// V reads feed 2 frags. LDS 64KB -> 2 blocks/CU.
// P buffer is 2 frags wide; PV runs pair {0,1}, P rewritten (wave-private,
// in-order DS), then pair {2,3}; frags 2,3's P parks in 16 VGPRs meanwhile.
// K/V staged via global_load_lds, double-buffered, counted vmcnt(6).
// ---------------------------------------------------------------------------
__global__ __launch_bounds__(256, 2)
void attn_mfma(const _Float16* __restrict__ Qhi, const _Float16* __restrict__ Qlo,
               const _Float16* __restrict__ Khi, const _Float16* __restrict__ Klo,
               const _Float16* __restrict__ Vt, _Float16* __restrict__ O)
{
    __shared__ _Float16 KhiS[2][64 * 64];
    __shared__ _Float16 KloS[2][64 * 64];
    __shared__ _Float16 VTS[2][64 * 64];   // [d][key]
    __shared__ _Float16 PWS[4][2048];      // per-wave: 2 frags x [16 q][64 key]

    const int tid = threadIdx.x;
    const int w = tid >> 6, lane = tid & 63;
    const int g = lane >> 4, q15 = lane & 15;
    _Float16* PW = PWS[w];

    const int qt = blockIdx.x, h = blockIdx.y, b = blockIdx.z;

    // ---- Q B-fragments: 4 frags (rows w*64 + f*16 + q15)
    half8 qh[4][2], ql[4][2];
    {
        size_t qoff = ((size_t)b * NN + qt * 256 + w * 64 + q15) * CC + h * 64 + g * 8;
#pragma unroll
        for (int f = 0; f < 4; ++f) {
            qh[f][0] = *reinterpret_cast<const half8*>(Qhi + qoff + f * 16 * CC);
            qh[f][1] = *reinterpret_cast<const half8*>(Qhi + qoff + f * 16 * CC + 32);
            ql[f][0] = *reinterpret_cast<const half8*>(Qlo + qoff + f * 16 * CC);
            ql[f][1] = *reinterpret_cast<const half8*>(Qlo + qoff + f * 16 * CC + 32);
        }
    }
    // drain Q loads so the loop's vmcnt counts only track staging
    asm volatile("s_waitcnt vmcnt(0)" ::: "memory");

    // ---- staging geometry: 256 threads cover rows 0..31 (+32 second issue),
    // linear LDS dest; global source pre-applies the inverse XOR swizzle.
    const int srow = tid >> 3, dg0 = tid & 7;
    const int scol = (dg0 ^ (srow & 7)) * 8;
    const _Float16* ksrc = Khi + ((size_t)b * NKK + srow) * CC + h * 64 + scol;
    const _Float16* lsrc = Klo + ((size_t)b * NKK + srow) * CC + h * 64 + scol;
    const _Float16* vsrc = Vt + ((size_t)b * CC + h * 64 + srow) * NKK + scol;

    f32x4 zero4 = {0.f, 0.f, 0.f, 0.f};
    f32x4 o[4][4];
#pragma unroll
    for (int f = 0; f < 4; ++f)
#pragma unroll
        for (int nt = 0; nt < 4; ++nt) o[f][nt] = zero4;
    float l[4] = {0.f, 0.f, 0.f, 0.f};

#define ISSUE(kt, buf)                                                             \
    {                                                                              \
        GLL16(ksrc + (size_t)(kt) * 64 * CC,           &KhiS[buf][w * 512]);       \
        GLL16(ksrc + (size_t)(kt) * 64 * CC + 32 * CC, &KhiS[buf][w * 512 + 2048]);\
        GLL16(lsrc + (size_t)(kt) * 64 * CC,           &KloS[buf][w * 512]);       \
        GLL16(lsrc + (size_t)(kt) * 64 * CC + 32 * CC, &KloS[buf][w * 512 + 2048]);\
        GLL16(vsrc + (kt) * 64,                        &VTS[buf][w * 512]);        \
        GLL16(vsrc + (kt) * 64 + 32 * NKK,             &VTS[buf][w * 512 + 2048]); \
    }

    ISSUE(0, 0);
    int cur = 0;

#pragma unroll 1
    for (int kt = 0; kt < 16; ++kt) {
        if (kt < 15) {
            ISSUE(kt + 1, cur ^ 1);
            asm volatile("s_waitcnt vmcnt(6)" ::: "memory");
        } else {
            asm volatile("s_waitcnt vmcnt(0)" ::: "memory");
        }
        __builtin_amdgcn_s_barrier();           // buf[cur] fully staged

        const _Float16* KH = KhiS[cur];
        const _Float16* KL = KloS[cur];
        const _Float16* VT = VTS[cur];

        float ls[4] = {0.f, 0.f, 0.f, 0.f};
        half4v p23[2][4];

        // ---- QK^T + softmax: shared ah/al reads feed all 4 frags
#pragma unroll
        for (int mt = 0; mt < 4; ++mt) {
            f32x4 sh[4], sl[4];
#pragma unroll
            for (int f = 0; f < 4; ++f) { sh[f] = zero4; sl[f] = zero4; }
            __builtin_amdgcn_s_setprio(1);
#pragma unroll
            for (int kc = 0; kc < 2; ++kc) {
                int key = mt * 16 + q15;
                int el = key * 64 + (((kc * 4 + g) ^ (key & 7)) * 8);
                half8 ah = *reinterpret_cast<const half8*>(&KH[el]);
                half8 al = *reinterpret_cast<const half8*>(&KL[el]);
#pragma unroll
                for (int f = 0; f < 4; ++f) {
                    sh[f] = MFMA16(ah, qh[f][kc], sh[f]);
                    sl[f] = MFMA16(ah, ql[f][kc], sl[f]);
                    sl[f] = MFMA16(al, qh[f][kc], sl[f]);
                }
            }
            __builtin_amdgcn_s_setprio(0);
            int el0 = q15 * 64 + (((mt * 2 + (g >> 1)) ^ (q15 & 7)) * 8) + (g & 1) * 4;
#pragma unroll
            for (int f = 0; f < 4; ++f) {
                half4v pk;
#pragma unroll
                for (int r = 0; r < 4; ++r) {
                    float sv = sh[f][r] + sl[f][r] * (1.0f / 256.0f);
                    float e = __expf(fabsf(sv));
                    ls[f] += e;
                    pk[r] = (_Float16)__builtin_copysignf(e, sv);
                }
                if (f < 2) *reinterpret_cast<half4v*>(&PW[el0 + f * 1024]) = pk;
                else        p23[f - 2][mt] = pk;
            }
        }
#pragma unroll
        for (int f = 0; f < 4; ++f) {
            ls[f] += __shfl_xor(ls[f], 16);
            ls[f] += __shfl_xor(ls[f], 32);
            l[f] += ls[f];
        }

        // ---- PV pair 0 (frags 0,1)
        __builtin_amdgcn_s_setprio(1);
#pragma unroll
        for (int kc = 0; kc < 2; ++kc) {
            const int blk = kc * 4 + g;
            int pel = q15 * 64 + ((blk ^ (q15 & 7)) * 8);
            half8 pa0 = *reinterpret_cast<const half8*>(&PW[pel]);
            half8 pa1 = *reinterpret_cast<const half8*>(&PW[pel + 1024]);
#pragma unroll
            for (int nt = 0; nt < 4; ++nt) {
                int d = nt * 16 + q15;
                int vel = d * 64 + ((blk ^ (d & 7)) * 8);
                half8 vb = *reinterpret_cast<const half8*>(&VT[vel]);
                o[0][nt] = MFMA16(pa0, vb, o[0][nt]);
                o[1][nt] = MFMA16(pa1, vb, o[1][nt]);
            }
        }
        __builtin_amdgcn_s_setprio(0);

        // ---- rewrite P with frags 2,3 (wave-private; DS ops in order)
#pragma unroll
        for (int mt = 0; mt < 4; ++mt) {
            int el0 = q15 * 64 + (((mt * 2 + (g >> 1)) ^ (q15 & 7)) * 8) + (g & 1) * 4;
            *reinterpret_cast<half4v*>(&PW[el0]) = p23[0][mt];
            *reinterpret_cast<half4v*>(&PW[el0 + 1024]) = p23[1][mt];
        }

        // ---- PV pair 1 (frags 2,3)
        __builtin_amdgcn_s_setprio(1);
#pragma unroll
        for (int kc = 0; kc < 2; ++kc) {
            const int blk = kc * 4 + g;
            int pel = q15 * 64 + ((blk ^ (q15 & 7)) * 8);
            half8 pa0 = *reinterpret_cast<const half8*>(&PW[pel]);
            half8 pa1 = *reinterpret_cast<const half8*>(&PW[pel + 1024]);
#pragma unroll
            for (int nt = 0; nt < 4; ++nt) {
                int d = nt * 16 + q15;
                int vel = d * 64 + ((blk ^ (d & 7)) * 8);
                half8 vb = *reinterpret_cast<const half8*>(&VT[vel]);
                o[2][nt] = MFMA16(pa0, vb, o[2][nt]);
                o[3][nt] = MFMA16(pa1, vb, o[3][nt]);
            }
        }
        __builtin_amdgcn_s_setprio(0);

        asm volatile("" ::: "memory");
        __builtin_amdgcn_s_barrier();           // all reads of buf[cur] done
        cur ^= 1;
    }
#undef ISSUE

    // ---- epilogue: O[q][d] / l  (O aliases Qlo: consumed above, unique owner)
#pragma unroll
    for (int f = 0; f < 4; ++f) {
        float rl = 1.0f / l[f];
        float rlq[4];
#pragma unroll
        for (int r = 0; r < 4; ++r) rlq[r] = __shfl(rl, g * 4 + r);
#pragma unroll
        for (int nt = 0; nt < 4; ++nt)
#pragma unroll
            for (int r = 0; r < 4; ++r) {
                size_t row = (size_t)b * NN + qt * 256 + w * 64 + f * 16 + g * 4 + r;
                O[row * CC + h * 64 + nt * 16 + q15] = (_Float16)(o[f][nt][r] * rlq[r]);
            }
    }
}

// ---------------------------------------------------------------------------
extern "C" void kernel_launch(void* const* d_in, const int* in_sizes, int n_in,
                              void* d_out, int out_size, void* d_ws, size_t ws_size,
                              hipStream_t stream) {
    const float* x   = (const float*)d_in[0];
    const float* Wq  = (const float*)d_in[1];
    const float* bq  = (const float*)d_in[2];
    const float* Wk  = (const float*)d_in[3];
    const float* bk  = (const float*)d_in[4];
    const float* Wv  = (const float*)d_in[5];
    const float* bv  = (const float*)d_in[6];
    const float* srw = (const float*)d_in[7];
    const float* srb = (const float*)d_in[8];
    const float* lng = (const float*)d_in[9];
    const float* lnb = (const float*)d_in[10];
    const float* Wp  = (const float*)d_in[11];
    const float* bp  = (const float*)d_in[12];
    float* out = (float*)d_out;

    // workspace layout (~43 MB)
    char* wsb = (char*)d_ws;
    _Float16* Qhi  = (_Float16*)wsb;                   // 12.58 MB
    _Float16* Qlo  = (_Float16*)(wsb + 12582912);      // 12.58 MB (also attn O)
    _Float16* XRhi = (_Float16*)(wsb + 25165824);      // 3.15 MB
    _Float16* XRlo = (_Float16*)(wsb + 28311552);      // 3.15 MB
    _Float16* Khi  = (_Float16*)(wsb + 31457280);      // 3.15 MB
    _Float16* Klo  = (_Float16*)(wsb + 34603008);      // 3.15 MB
    _Float16* Vt   = (_Float16*)(wsb + 37748736);      // 3.15 MB [b][c][nk]
    _Float16* Wqh  = (_Float16*)(wsb + 40894464);      // 7 x 0.295 MB
    _Float16* Wql  = Wqh + 147456;
    _Float16* Wkh  = Wql + 147456;
    _Float16* Wkl  = Wkh + 147456;
    _Float16* Wvh  = Wkl + 147456;
    _Float16* Wvl  = Wvh + 147456;
    _Float16* Wph  = Wvl + 147456;
    _Float16* Ob   = Qlo;

    split_w<<<dim3(576), 256, 0, stream>>>(Wq, Wk, Wv, Wp, Wqh, Wql, Wkh, Wkl, Wvh, Wvl, Wph);
    // Q projection: (x @ Wq^T + bq) * 0.125, split pair out
    gemm_mf<0, 1, 0><<<dim3(128, 6), 256, 0, stream>>>(
        x, nullptr, Wqh, Wql, bq, Qhi, Qlo, nullptr, 0.125f);
    // spatial-reduction conv + LN -> pre-split f16 pair
    srconv_ln<<<dim3(BB * NKK), dim3(128), 0, stream>>>(x, srw, srb, lng, lnb, XRhi, XRlo);
    // K projection (pair out), V projection (transposed f16 out)
    gemm_mf<1, 1, 0><<<dim3(32, 6), 256, 0, stream>>>(
        XRhi, XRlo, Wkh, Wkl, bk, Khi, Klo, nullptr, 1.0f);
    gemm_mf<1, 1, 1><<<dim3(32, 6), 256, 0, stream>>>(
        XRhi, XRlo, Wvh, Wvl, bv, Vt, nullptr, nullptr, 1.0f);
    // fused attention (256 q rows per block, 4 waves x 64 rows)
    attn_mfma<<<dim3(16, 6, 4), 256, 0, stream>>>(Qhi, Qlo, Khi, Klo, Vt, Ob);
    // output projection -> d_out (f32)
    gemm_mf<2, 2, 2><<<dim3(128, 6), 256, 0, stream>>>(
        Ob, nullptr, Wph, nullptr, bp, nullptr, nullptr, out, 1.0f);
}

// Round 8
// 143.063 us; speedup vs baseline: 1.0354x; 1.0354x over previous
//
#include <hip/hip_runtime.h>
#include <hip/hip_bf16.h>
#include <math.h>

#define BB 4
#define NN 4096
#define CC 384
#define NHH 6
#define HDD 64
#define NKK 1024
#define LN_EPS 1e-5f

typedef _Float16 half8 __attribute__((ext_vector_type(8)));
typedef _Float16 half4v __attribute__((ext_vector_type(4)));
typedef _Float16 half2v __attribute__((ext_vector_type(2)));
typedef float f32x4 __attribute__((ext_vector_type(4)));

#define MFMA16(a, b, c) __builtin_amdgcn_mfma_f32_16x16x32_f16((a), (b), (c), 0, 0, 0)

#define GLL16(src, dst)                                                       \
    __builtin_amdgcn_global_load_lds(                                         \
        (const __attribute__((address_space(1))) void*)(src),                 \
        (__attribute__((address_space(3))) void*)(dst), 16, 0, 0)

// ---------------------------------------------------------------------------
// Weight pre-split: Wq,Wk,Wv -> f16 hi/lo pairs; Wp -> f16.
// ---------------------------------------------------------------------------
__global__ __launch_bounds__(256)
void split_w(const float* __restrict__ Wq, const float* __restrict__ Wk,
             const float* __restrict__ Wv, const float* __restrict__ Wp,
             _Float16* __restrict__ qh, _Float16* __restrict__ ql,
             _Float16* __restrict__ kh, _Float16* __restrict__ kl,
             _Float16* __restrict__ vh, _Float16* __restrict__ vl,
             _Float16* __restrict__ ph) {
    int i = blockIdx.x * 256 + threadIdx.x;   // 384*384 = 147456
    float q = Wq[i], k = Wk[i], v = Wv[i], p = Wp[i];
    _Float16 h;
    h = (_Float16)q; qh[i] = h; ql[i] = (_Float16)((q - (float)h) * 256.0f);
    h = (_Float16)k; kh[i] = h; kl[i] = (_Float16)((k - (float)h) * 256.0f);
    h = (_Float16)v; vh[i] = h; vl[i] = (_Float16)((v - (float)h) * 256.0f);
    ph[i] = (_Float16)p;
}

// ---------------------------------------------------------------------------
// Split-f16 MFMA GEMM (unchanged):
// Y = (A(MxK) @ W(NxK)^T + bias) * scale, K=N=384.
// AIN: 0 = f32 A (split on stage), 1 = pre-split f16 pair, 2 = f16 single
// WIN: 1 = pre-split f16 pair, 2 = f16 single
// OUT: 0 = f16 pair, 1 = f16 transposed Vt[b][c][nk], 2 = f32
// ---------------------------------------------------------------------------
template<int AIN, int WIN, int OUT>
__global__ __launch_bounds__(256) void gemm_mf(
    const void* __restrict__ A0, const void* __restrict__ A1,
    const _Float16* __restrict__ Whi, const _Float16* __restrict__ Wlo,
    const float* __restrict__ bias, _Float16* __restrict__ Yhi,
    _Float16* __restrict__ Ylo, float* __restrict__ Yf, float scale)
{
    constexpr bool SPLIT = (AIN != 2);
    __shared__ _Float16 AhiS[128 * 64];
    __shared__ _Float16 AloS[SPLIT ? 128 * 64 : 64];
    __shared__ _Float16 WhiS[64 * 64];
    __shared__ _Float16 WloS[(WIN == 1) ? 64 * 64 : 64];

    const int tid = threadIdx.x;
    const int bm = blockIdx.x * 128;
    const int bn = blockIdx.y * 64;
    const int w = tid >> 6, lane = tid & 63;
    const int g = lane >> 4, n15 = lane & 15;

    f32x4 zero4 = {0.f, 0.f, 0.f, 0.f};
    f32x4 acc_hi[2][4], acc_lo[SPLIT ? 2 : 1][SPLIT ? 4 : 1];
#pragma unroll
    for (int mf = 0; mf < 2; ++mf)
#pragma unroll
        for (int nt = 0; nt < 4; ++nt) {
            acc_hi[mf][nt] = zero4;
            if (SPLIT) acc_lo[mf][nt] = zero4;
        }

    for (int k0 = 0; k0 < CC; k0 += 64) {
        __syncthreads();
        if (AIN == 0) {
            const float* A = (const float*)A0;
#pragma unroll
            for (int i = 0; i < 8; ++i) {
                int id = tid + 256 * i;
                int row = id >> 4, c4 = (id & 15) * 4;
                float4 av = *reinterpret_cast<const float4*>(A + (size_t)(bm + row) * CC + k0 + c4);
                int el = row * 64 + (((c4 >> 3) ^ (row & 7)) * 8) + (c4 & 7);
                float vv[4] = {av.x, av.y, av.z, av.w};
                half4v hi, lo;
#pragma unroll
                for (int e = 0; e < 4; ++e) {
                    _Float16 h = (_Float16)vv[e];
                    hi[e] = h;
                    lo[e] = (_Float16)((vv[e] - (float)h) * 256.0f);
                }
                *reinterpret_cast<half4v*>(&AhiS[el]) = hi;
                *reinterpret_cast<half4v*>(&AloS[el]) = lo;
            }
        } else if (AIN == 1) {
            const _Float16* Ah = (const _Float16*)A0;
            const _Float16* Al = (const _Float16*)A1;
#pragma unroll
            for (int i = 0; i < 4; ++i) {
                int id = tid + 256 * i;
                int row = id >> 3, dg = id & 7;
                size_t go = (size_t)(bm + row) * CC + k0 + dg * 8;
                half8 hv = *reinterpret_cast<const half8*>(Ah + go);
                half8 lv = *reinterpret_cast<const half8*>(Al + go);
                int el = row * 64 + ((dg ^ (row & 7)) * 8);
                *reinterpret_cast<half8*>(&AhiS[el]) = hv;
                *reinterpret_cast<half8*>(&AloS[el]) = lv;
            }
        } else {
            const _Float16* A = (const _Float16*)A0;
#pragma unroll
            for (int i = 0; i < 4; ++i) {
                int id = tid + 256 * i;
                int row = id >> 3, dg = id & 7;
                half8 av = *reinterpret_cast<const half8*>(A + (size_t)(bm + row) * CC + k0 + dg * 8);
                int el = row * 64 + ((dg ^ (row & 7)) * 8);
                *reinterpret_cast<half8*>(&AhiS[el]) = av;
            }
        }
#pragma unroll
        for (int i = 0; i < 2; ++i) {
            int id = tid + 256 * i;
            int row = id >> 3, dg = id & 7;
            size_t go = (size_t)(bn + row) * CC + k0 + dg * 8;
            half8 wh = *reinterpret_cast<const half8*>(Whi + go);
            int el = row * 64 + ((dg ^ (row & 7)) * 8);
            *reinterpret_cast<half8*>(&WhiS[el]) = wh;
            if (WIN == 1) {
                half8 wl = *reinterpret_cast<const half8*>(Wlo + go);
                *reinterpret_cast<half8*>(&WloS[el]) = wl;
            }
        }
        __syncthreads();
#pragma unroll
        for (int kc = 0; kc < 2; ++kc) {
            const int blk = kc * 4 + g;
            half8 a_hi[2], a_lo[2], b_hi[4], b_lo[4];
#pragma unroll
            for (int mf = 0; mf < 2; ++mf) {
                int row = w * 32 + mf * 16 + n15;
                int el = row * 64 + ((blk ^ (row & 7)) * 8);
                a_hi[mf] = *reinterpret_cast<const half8*>(&AhiS[el]);
                if (SPLIT) a_lo[mf] = *reinterpret_cast<const half8*>(&AloS[el]);
            }
#pragma unroll
            for (int nt = 0; nt < 4; ++nt) {
                int row = nt * 16 + n15;
                int el = row * 64 + ((blk ^ (row & 7)) * 8);
                b_hi[nt] = *reinterpret_cast<const half8*>(&WhiS[el]);
                if (WIN == 1) b_lo[nt] = *reinterpret_cast<const half8*>(&WloS[el]);
            }
#pragma unroll
            for (int mf = 0; mf < 2; ++mf)
#pragma unroll
                for (int nt = 0; nt < 4; ++nt) {
                    acc_hi[mf][nt] = MFMA16(a_hi[mf], b_hi[nt], acc_hi[mf][nt]);
                    if (SPLIT) {
                        acc_lo[mf][nt] = MFMA16(a_hi[mf], b_lo[nt], acc_lo[mf][nt]);
                        acc_lo[mf][nt] = MFMA16(a_lo[mf], b_hi[nt], acc_lo[mf][nt]);
                    }
                }
        }
    }
#pragma unroll
    for (int nt = 0; nt < 4; ++nt) {
        int col = bn + nt * 16 + n15;
        float bc = bias[col];
#pragma unroll
        for (int mf = 0; mf < 2; ++mf)
#pragma unroll
            for (int r = 0; r < 4; ++r) {
                size_t row = bm + w * 32 + mf * 16 + g * 4 + r;
                float y = acc_hi[mf][nt][r];
                if (SPLIT) y += acc_lo[mf][nt][r] * (1.0f / 256.0f);
                y = (y + bc) * scale;
                if (OUT == 0) {
                    _Float16 h = (_Float16)y;
                    Yhi[row * CC + col] = h;
                    Ylo[row * CC + col] = (_Float16)((y - (float)h) * 256.0f);
                } else if (OUT == 1) {
                    Yhi[((row >> 10) * CC + col) * NKK + (row & 1023)] = (_Float16)y;
                } else {
                    Yf[row * CC + col] = y;
                }
            }
    }
}

// ---------------------------------------------------------------------------
// Depthwise 2x2 stride-2 conv (VALID) + LayerNorm; writes f16 hi/lo pair.
// ---------------------------------------------------------------------------
__global__ __launch_bounds__(128)
void srconv_ln(const float* __restrict__ x, const float* __restrict__ srw,
               const float* __restrict__ srb, const float* __restrict__ g,
               const float* __restrict__ beta,
               _Float16* __restrict__ xrh, _Float16* __restrict__ xrl) {
    const int row = blockIdx.x;
    const int b  = row >> 10;
    const int nk = row & 1023;
    const int oy = nk >> 5;
    const int ox = nk & 31;
    const int n0 = (2 * oy) * 64 + 2 * ox;
    const float* xb = x + ((size_t)b * NN + n0) * CC;
    const int tid = threadIdx.x;

    float vals[3];
    float lsum = 0.f, lsum2 = 0.f;
#pragma unroll
    for (int i = 0; i < 3; ++i) {
        const int c = tid + i * 128;
        const float4 w = *reinterpret_cast<const float4*>(srw + (size_t)c * 4);
        float v = xb[c] * w.x + xb[CC + c] * w.y +
                  xb[(size_t)64 * CC + c] * w.z + xb[(size_t)65 * CC + c] * w.w + srb[c];
        vals[i] = v;
        lsum += v;
        lsum2 += v * v;
    }
#pragma unroll
    for (int off = 32; off; off >>= 1) {
        lsum  += __shfl_down(lsum, off);
        lsum2 += __shfl_down(lsum2, off);
    }
    __shared__ float ssum[2], ssum2[2];
    if ((tid & 63) == 0) { ssum[tid >> 6] = lsum; ssum2[tid >> 6] = lsum2; }
    __syncthreads();
    const float tot  = ssum[0] + ssum[1];
    const float tot2 = ssum2[0] + ssum2[1];
    const float mu  = tot * (1.0f / 384.0f);
    const float var = tot2 * (1.0f / 384.0f) - mu * mu;
    const float rstd = 1.0f / sqrtf(var + LN_EPS);

    _Float16* oh = xrh + (size_t)row * CC;
    _Float16* ol = xrl + (size_t)row * CC;
#pragma unroll
    for (int i = 0; i < 3; ++i) {
        const int c = tid + i * 128;
        float v = (vals[i] - mu) * rstd * g[c] + beta[c];
        _Float16 h = (_Float16)v;
        oh[c] = h;
        ol[c] = (_Float16)((v - (float)h) * 256.0f);
    }
}

// ---------------------------------------------------------------------------
// Fused MFMA attention, neg-softmax, m == 0 (linear accumulation).
// v8: QT=128, 4 waves x 32 q-rows (2 frags); KVBLK=32, 32 kt iters.
// Grid 32x6x4 = 768 = exactly 3 blocks/CU; LDS 32 KB -> all 3 resident
// (12 waves/CU uniform). K/V double-buffered via global_load_lds with
// counted vmcnt(3). Shared K reads feed 6 MFMAs, V reads feed 2.
// ---------------------------------------------------------------------------
__global__ __launch_bounds__(256, 3)
void attn_mfma(const _Float16* __restrict__ Qhi, const _Float16* __restrict__ Qlo,
               const _Float16* __restrict__ Khi, const _Float16* __restrict__ Klo,
               const _Float16* __restrict__ Vt, _Float16* __restrict__ O)
{
    __shared__ _Float16 KhiS[2][32 * 64];   // [key][d]
    __shared__ _Float16 KloS[2][32 * 64];
    __shared__ _Float16 VTS[2][64 * 32];    // [d][key]
    __shared__ _Float16 PWS[4][1024];       // per-wave: 2 frags x [16 q][32 key]

    const int tid = threadIdx.x;
    const int w = tid >> 6, lane = tid & 63;
    const int g = lane >> 4, q15 = lane & 15;
    _Float16* PW = PWS[w];

    const int qt = blockIdx.x, h = blockIdx.y, b = blockIdx.z;

    // ---- Q B-fragments: 2 frags (rows qt*128 + w*32 + f*16 + q15)
    half8 qh[2][2], ql[2][2];
    {
        size_t qoff = ((size_t)b * NN + qt * 128 + w * 32 + q15) * CC + h * 64 + g * 8;
#pragma unroll
        for (int f = 0; f < 2; ++f) {
            qh[f][0] = *reinterpret_cast<const half8*>(Qhi + qoff + f * 16 * CC);
            qh[f][1] = *reinterpret_cast<const half8*>(Qhi + qoff + f * 16 * CC + 32);
            ql[f][0] = *reinterpret_cast<const half8*>(Qlo + qoff + f * 16 * CC);
            ql[f][1] = *reinterpret_cast<const half8*>(Qlo + qoff + f * 16 * CC + 32);
        }
    }
    // drain Q loads so the loop's vmcnt counts only track staging
    asm volatile("s_waitcnt vmcnt(0)" ::: "memory");

    // ---- staging geometry (256 thr): K tiles [32 key][64 d] -> thread covers
    // key=tid>>3, d-block=tid&7 (inverse-XOR-swizzled global source, linear
    // LDS dest). V tile [64 d][32 key]: d=tid>>2, key-block=tid&3.
    const int krow = tid >> 3, kdg = tid & 7;
    const int kscol = (kdg ^ (krow & 7)) * 8;
    const _Float16* ksrc = Khi + ((size_t)b * NKK + krow) * CC + h * 64 + kscol;
    const _Float16* lsrc = Klo + ((size_t)b * NKK + krow) * CC + h * 64 + kscol;
    const int vd = tid >> 2, vkb = tid & 3;
    const _Float16* vsrc = Vt + ((size_t)b * CC + h * 64 + vd) * NKK + ((vkb ^ (vd & 3)) * 8);

    f32x4 zero4 = {0.f, 0.f, 0.f, 0.f};
    f32x4 o[2][4];
#pragma unroll
    for (int f = 0; f < 2; ++f)
#pragma unroll
        for (int nt = 0; nt < 4; ++nt) o[f][nt] = zero4;
    float l[2] = {0.f, 0.f};

#define ISSUE(kt, buf)                                                        \
    {                                                                         \
        GLL16(ksrc + (size_t)(kt) * 32 * CC, &KhiS[buf][tid * 8]);            \
        GLL16(lsrc + (size_t)(kt) * 32 * CC, &KloS[buf][tid * 8]);            \
        GLL16(vsrc + (kt) * 32,              &VTS[buf][tid * 8]);             \
    }

    ISSUE(0, 0);
    int cur = 0;

#pragma unroll 1
    for (int kt = 0; kt < 32; ++kt) {
        if (kt < 31) {
            ISSUE(kt + 1, cur ^ 1);
            asm volatile("s_waitcnt vmcnt(3)" ::: "memory");
        } else {
            asm volatile("s_waitcnt vmcnt(0)" ::: "memory");
        }
        __builtin_amdgcn_s_barrier();           // buf[cur] fully staged

        const _Float16* KH = KhiS[cur];
        const _Float16* KL = KloS[cur];
        const _Float16* VT = VTS[cur];
        float ls[2] = {0.f, 0.f};

        // ---- QK^T + softmax (shared ah/al reads feed both frags)
#pragma unroll
        for (int mt = 0; mt < 2; ++mt) {
            f32x4 sh[2], sl[2];
#pragma unroll
            for (int f = 0; f < 2; ++f) { sh[f] = zero4; sl[f] = zero4; }
            __builtin_amdgcn_s_setprio(1);
#pragma unroll
            for (int kc = 0; kc < 2; ++kc) {
                int key = mt * 16 + q15;
                int el = key * 64 + (((kc * 4 + g) ^ (key & 7)) * 8);
                half8 ah = *reinterpret_cast<const half8*>(&KH[el]);
                half8 al = *reinterpret_cast<const half8*>(&KL[el]);
#pragma unroll
                for (int f = 0; f < 2; ++f) {
                    sh[f] = MFMA16(ah, qh[f][kc], sh[f]);
                    sl[f] = MFMA16(ah, ql[f][kc], sl[f]);
                    sl[f] = MFMA16(al, qh[f][kc], sl[f]);
                }
            }
            __builtin_amdgcn_s_setprio(0);
            // P write: keys mt*16 + g*4 .. +3 ; [16 q][32 key] XOR-swizzled
            int elw = q15 * 32 + (((mt * 2 + (g >> 1)) ^ (q15 & 3)) * 8) + (g & 1) * 4;
#pragma unroll
            for (int f = 0; f < 2; ++f) {
                half4v pk;
#pragma unroll
                for (int r = 0; r < 4; ++r) {
                    float sv = sh[f][r] + sl[f][r] * (1.0f / 256.0f);
                    float e = __expf(fabsf(sv));
                    ls[f] += e;
                    pk[r] = (_Float16)__builtin_copysignf(e, sv);
                }
                *reinterpret_cast<half4v*>(&PW[elw + f * 512]) = pk;
            }
        }
#pragma unroll
        for (int f = 0; f < 2; ++f) {
            ls[f] += __shfl_xor(ls[f], 16);
            ls[f] += __shfl_xor(ls[f], 32);
            l[f] += ls[f];
        }

        // ---- PV: O[q][d] += P[q][key] * V[key][d]  (vb shared by both frags)
        __builtin_amdgcn_s_setprio(1);
        {
            int pel = q15 * 32 + ((g ^ (q15 & 3)) * 8);
            half8 pa0 = *reinterpret_cast<const half8*>(&PW[pel]);
            half8 pa1 = *reinterpret_cast<const half8*>(&PW[pel + 512]);
#pragma unroll
            for (int nt = 0; nt < 4; ++nt) {
                int d = nt * 16 + q15;
                int vel = d * 32 + ((g ^ (d & 3)) * 8);
                half8 vb = *reinterpret_cast<const half8*>(&VT[vel]);
                o[0][nt] = MFMA16(pa0, vb, o[0][nt]);
                o[1][nt] = MFMA16(pa1, vb, o[1][nt]);
            }
        }
        __builtin_amdgcn_s_setprio(0);

        asm volatile("" ::: "memory");
        __builtin_amdgcn_s_barrier();           // all reads of buf[cur] done
        cur ^= 1;
    }
#undef ISSUE

    // ---- epilogue: O[q][d] / l  (O aliases Qlo: consumed above, unique owner)
#pragma unroll
    for (int f = 0; f < 2; ++f) {
        float rl = 1.0f / l[f];
        float rlq[4];
#pragma unroll
        for (int r = 0; r < 4; ++r) rlq[r] = __shfl(rl, g * 4 + r);
#pragma unroll
        for (int nt = 0; nt < 4; ++nt)
#pragma unroll
            for (int r = 0; r < 4; ++r) {
                size_t row = (size_t)b * NN + qt * 128 + w * 32 + f * 16 + g * 4 + r;
                O[row * CC + h * 64 + nt * 16 + q15] = (_Float16)(o[f][nt][r] * rlq[r]);
            }
    }
}

// ---------------------------------------------------------------------------
extern "C" void kernel_launch(void* const* d_in, const int* in_sizes, int n_in,
                              void* d_out, int out_size, void* d_ws, size_t ws_size,
                              hipStream_t stream) {
    const float* x   = (const float*)d_in[0];
    const float* Wq  = (const float*)d_in[1];
    const float* bq  = (const float*)d_in[2];
    const float* Wk  = (const float*)d_in[3];
    const float* bk  = (const float*)d_in[4];
    const float* Wv  = (const float*)d_in[5];
    const float* bv  = (const float*)d_in[6];
    const float* srw = (const float*)d_in[7];
    const float* srb = (const float*)d_in[8];
    const float* lng = (const float*)d_in[9];
    const float* lnb = (const float*)d_in[10];
    const float* Wp  = (const float*)d_in[11];
    const float* bp  = (const float*)d_in[12];
    float* out = (float*)d_out;

    // workspace layout (~43 MB)
    char* wsb = (char*)d_ws;
    _Float16* Qhi  = (_Float16*)wsb;                   // 12.58 MB
    _Float16* Qlo  = (_Float16*)(wsb + 12582912);      // 12.58 MB (also attn O)
    _Float16* XRhi = (_Float16*)(wsb + 25165824);      // 3.15 MB
    _Float16* XRlo = (_Float16*)(wsb + 28311552);      // 3.15 MB
    _Float16* Khi  = (_Float16*)(wsb + 31457280);      // 3.15 MB
    _Float16* Klo  = (_Float16*)(wsb + 34603008);      // 3.15 MB
    _Float16* Vt   = (_Float16*)(wsb + 37748736);      // 3.15 MB [b][c][nk]
    _Float16* Wqh  = (_Float16*)(wsb + 40894464);      // 7 x 0.295 MB
    _Float16* Wql  = Wqh + 147456;
    _Float16* Wkh  = Wql + 147456;
    _Float16* Wkl  = Wkh + 147456;
    _Float16* Wvh  = Wkl + 147456;
    _Float16* Wvl  = Wvh + 147456;
    _Float16* Wph  = Wvl + 147456;
    _Float16* Ob   = Qlo;

    split_w<<<dim3(576), 256, 0, stream>>>(Wq, Wk, Wv, Wp, Wqh, Wql, Wkh, Wkl, Wvh, Wvl, Wph);
    // Q projection: (x @ Wq^T + bq) * 0.125, split pair out
    gemm_mf<0, 1, 0><<<dim3(128, 6), 256, 0, stream>>>(
        x, nullptr, Wqh, Wql, bq, Qhi, Qlo, nullptr, 0.125f);
    // spatial-reduction conv + LN -> pre-split f16 pair
    srconv_ln<<<dim3(BB * NKK), dim3(128), 0, stream>>>(x, srw, srb, lng, lnb, XRhi, XRlo);
    // K projection (pair out), V projection (transposed f16 out)
    gemm_mf<1, 1, 0><<<dim3(32, 6), 256, 0, stream>>>(
        XRhi, XRlo, Wkh, Wkl, bk, Khi, Klo, nullptr, 1.0f);
    gemm_mf<1, 1, 1><<<dim3(32, 6), 256, 0, stream>>>(
        XRhi, XRlo, Wvh, Wvl, bv, Vt, nullptr, nullptr, 1.0f);
    // fused attention (128 q rows per block, 4 waves x 32 rows, 3 blocks/CU)
    attn_mfma<<<dim3(32, 6, 4), 256, 0, stream>>>(Qhi, Qlo, Khi, Klo, Vt, Ob);
    // output projection -> d_out (f32)
    gemm_mf<2, 2, 2><<<dim3(128, 6), 256, 0, stream>>>(
        Ob, nullptr, Wph, nullptr, bp, nullptr, nullptr, out, 1.0f);
}

// Round 9
// 129.375 us; speedup vs baseline: 1.1450x; 1.1058x over previous
//
#include <hip/hip_runtime.h>
#include <hip/hip_bf16.h>
#include <math.h>

#define BB 4
#define NN 4096
#define CC 384
#define NHH 6
#define HDD 64
#define NKK 1024
#define LN_EPS 1e-5f

typedef _Float16 half8 __attribute__((ext_vector_type(8)));
typedef _Float16 half4v __attribute__((ext_vector_type(4)));
typedef _Float16 half2v __attribute__((ext_vector_type(2)));
typedef float f32x4 __attribute__((ext_vector_type(4)));

#define MFMA16(a, b, c) __builtin_amdgcn_mfma_f32_16x16x32_f16((a), (b), (c), 0, 0, 0)

#define GLL16(src, dst)                                                       \
    __builtin_amdgcn_global_load_lds(                                         \
        (const __attribute__((address_space(1))) void*)(src),                 \
        (__attribute__((address_space(3))) void*)(dst), 16, 0, 0)

// ---------------------------------------------------------------------------
// Split-f16 MFMA GEMM (Q-proj / out-proj variants, unchanged math):
// Y = (A(MxK) @ W(NxK)^T + bias) * scale, K=N=384.
// AIN: 0 = f32 A (split on stage), 2 = f16 single
// WIN: 1 = pre-split f16 pair, 2 = f16 single
// OUT: 0 = f16 pair, 2 = f32
// ---------------------------------------------------------------------------
template<int AIN, int WIN, int OUT>
__global__ __launch_bounds__(256) void gemm_mf(
    const void* __restrict__ A0, const void* __restrict__ A1,
    const _Float16* __restrict__ Whi, const _Float16* __restrict__ Wlo,
    const float* __restrict__ bias, _Float16* __restrict__ Yhi,
    _Float16* __restrict__ Ylo, float* __restrict__ Yf, float scale)
{
    constexpr bool SPLIT = (AIN != 2);
    __shared__ _Float16 AhiS[128 * 64];
    __shared__ _Float16 AloS[SPLIT ? 128 * 64 : 64];
    __shared__ _Float16 WhiS[64 * 64];
    __shared__ _Float16 WloS[(WIN == 1) ? 64 * 64 : 64];

    const int tid = threadIdx.x;
    const int bm = blockIdx.x * 128;
    const int bn = blockIdx.y * 64;
    const int w = tid >> 6, lane = tid & 63;
    const int g = lane >> 4, n15 = lane & 15;

    f32x4 zero4 = {0.f, 0.f, 0.f, 0.f};
    f32x4 acc_hi[2][4], acc_lo[SPLIT ? 2 : 1][SPLIT ? 4 : 1];
#pragma unroll
    for (int mf = 0; mf < 2; ++mf)
#pragma unroll
        for (int nt = 0; nt < 4; ++nt) {
            acc_hi[mf][nt] = zero4;
            if (SPLIT) acc_lo[mf][nt] = zero4;
        }

    for (int k0 = 0; k0 < CC; k0 += 64) {
        __syncthreads();
        if (AIN == 0) {
            const float* A = (const float*)A0;
#pragma unroll
            for (int i = 0; i < 8; ++i) {
                int id = tid + 256 * i;
                int row = id >> 4, c4 = (id & 15) * 4;
                float4 av = *reinterpret_cast<const float4*>(A + (size_t)(bm + row) * CC + k0 + c4);
                int el = row * 64 + (((c4 >> 3) ^ (row & 7)) * 8) + (c4 & 7);
                float vv[4] = {av.x, av.y, av.z, av.w};
                half4v hi, lo;
#pragma unroll
                for (int e = 0; e < 4; ++e) {
                    _Float16 h = (_Float16)vv[e];
                    hi[e] = h;
                    lo[e] = (_Float16)((vv[e] - (float)h) * 256.0f);
                }
                *reinterpret_cast<half4v*>(&AhiS[el]) = hi;
                *reinterpret_cast<half4v*>(&AloS[el]) = lo;
            }
        } else {
            const _Float16* A = (const _Float16*)A0;
#pragma unroll
            for (int i = 0; i < 4; ++i) {
                int id = tid + 256 * i;
                int row = id >> 3, dg = id & 7;
                half8 av = *reinterpret_cast<const half8*>(A + (size_t)(bm + row) * CC + k0 + dg * 8);
                int el = row * 64 + ((dg ^ (row & 7)) * 8);
                *reinterpret_cast<half8*>(&AhiS[el]) = av;
            }
        }
#pragma unroll
        for (int i = 0; i < 2; ++i) {
            int id = tid + 256 * i;
            int row = id >> 3, dg = id & 7;
            size_t go = (size_t)(bn + row) * CC + k0 + dg * 8;
            half8 wh = *reinterpret_cast<const half8*>(Whi + go);
            int el = row * 64 + ((dg ^ (row & 7)) * 8);
            *reinterpret_cast<half8*>(&WhiS[el]) = wh;
            if (WIN == 1) {
                half8 wl = *reinterpret_cast<const half8*>(Wlo + go);
                *reinterpret_cast<half8*>(&WloS[el]) = wl;
            }
        }
        __syncthreads();
#pragma unroll
        for (int kc = 0; kc < 2; ++kc) {
            const int blk = kc * 4 + g;
            half8 a_hi[2], a_lo[2], b_hi[4], b_lo[4];
#pragma unroll
            for (int mf = 0; mf < 2; ++mf) {
                int row = w * 32 + mf * 16 + n15;
                int el = row * 64 + ((blk ^ (row & 7)) * 8);
                a_hi[mf] = *reinterpret_cast<const half8*>(&AhiS[el]);
                if (SPLIT) a_lo[mf] = *reinterpret_cast<const half8*>(&AloS[el]);
            }
#pragma unroll
            for (int nt = 0; nt < 4; ++nt) {
                int row = nt * 16 + n15;
                int el = row * 64 + ((blk ^ (row & 7)) * 8);
                b_hi[nt] = *reinterpret_cast<const half8*>(&WhiS[el]);
                if (WIN == 1) b_lo[nt] = *reinterpret_cast<const half8*>(&WloS[el]);
            }
#pragma unroll
            for (int mf = 0; mf < 2; ++mf)
#pragma unroll
                for (int nt = 0; nt < 4; ++nt) {
                    acc_hi[mf][nt] = MFMA16(a_hi[mf], b_hi[nt], acc_hi[mf][nt]);
                    if (SPLIT) {
                        acc_lo[mf][nt] = MFMA16(a_hi[mf], b_lo[nt], acc_lo[mf][nt]);
                        acc_lo[mf][nt] = MFMA16(a_lo[mf], b_hi[nt], acc_lo[mf][nt]);
                    }
                }
        }
    }
#pragma unroll
    for (int nt = 0; nt < 4; ++nt) {
        int col = bn + nt * 16 + n15;
        float bc = bias[col];
#pragma unroll
        for (int mf = 0; mf < 2; ++mf)
#pragma unroll
            for (int r = 0; r < 4; ++r) {
                size_t row = bm + w * 32 + mf * 16 + g * 4 + r;
                float y = acc_hi[mf][nt][r];
                if (SPLIT) y += acc_lo[mf][nt][r] * (1.0f / 256.0f);
                y = (y + bc) * scale;
                if (OUT == 0) {
                    _Float16 h = (_Float16)y;
                    Yhi[row * CC + col] = h;
                    Ylo[row * CC + col] = (_Float16)((y - (float)h) * 256.0f);
                } else {
                    Yf[row * CC + col] = y;
                }
            }
    }
}

// ---------------------------------------------------------------------------
// Fused K-proj + V-proj (AIN=1 pre-split pair, WIN=1). blockIdx.z: 0 -> K
// (writes f16 pair), 1 -> V (writes transposed Vt[b][c][nk]). Saves a launch
// (inter-dispatch gap) vs two kernels; bodies identical to gemm_mf<1,1,*>.
// ---------------------------------------------------------------------------
__global__ __launch_bounds__(256) void gemm_kv(
    const _Float16* __restrict__ Ah, const _Float16* __restrict__ Al,
    const _Float16* __restrict__ Wkh, const _Float16* __restrict__ Wkl,
    const _Float16* __restrict__ Wvh, const _Float16* __restrict__ Wvl,
    const float* __restrict__ bk, const float* __restrict__ bv,
    _Float16* __restrict__ Khi, _Float16* __restrict__ Klo,
    _Float16* __restrict__ Vt)
{
    __shared__ _Float16 AhiS[128 * 64];
    __shared__ _Float16 AloS[128 * 64];
    __shared__ _Float16 WhiS[64 * 64];
    __shared__ _Float16 WloS[64 * 64];

    const int tid = threadIdx.x;
    const int bm = blockIdx.x * 128;
    const int bn = blockIdx.y * 64;
    const int isV = blockIdx.z;
    const _Float16* Whi = isV ? Wvh : Wkh;
    const _Float16* Wlo = isV ? Wvl : Wkl;
    const float* bias = isV ? bv : bk;
    const int w = tid >> 6, lane = tid & 63;
    const int g = lane >> 4, n15 = lane & 15;

    f32x4 zero4 = {0.f, 0.f, 0.f, 0.f};
    f32x4 acc_hi[2][4], acc_lo[2][4];
#pragma unroll
    for (int mf = 0; mf < 2; ++mf)
#pragma unroll
        for (int nt = 0; nt < 4; ++nt) { acc_hi[mf][nt] = zero4; acc_lo[mf][nt] = zero4; }

    for (int k0 = 0; k0 < CC; k0 += 64) {
        __syncthreads();
#pragma unroll
        for (int i = 0; i < 4; ++i) {
            int id = tid + 256 * i;
            int row = id >> 3, dg = id & 7;
            size_t go = (size_t)(bm + row) * CC + k0 + dg * 8;
            half8 hv = *reinterpret_cast<const half8*>(Ah + go);
            half8 lv = *reinterpret_cast<const half8*>(Al + go);
            int el = row * 64 + ((dg ^ (row & 7)) * 8);
            *reinterpret_cast<half8*>(&AhiS[el]) = hv;
            *reinterpret_cast<half8*>(&AloS[el]) = lv;
        }
#pragma unroll
        for (int i = 0; i < 2; ++i) {
            int id = tid + 256 * i;
            int row = id >> 3, dg = id & 7;
            size_t go = (size_t)(bn + row) * CC + k0 + dg * 8;
            half8 wh = *reinterpret_cast<const half8*>(Whi + go);
            half8 wl = *reinterpret_cast<const half8*>(Wlo + go);
            int el = row * 64 + ((dg ^ (row & 7)) * 8);
            *reinterpret_cast<half8*>(&WhiS[el]) = wh;
            *reinterpret_cast<half8*>(&WloS[el]) = wl;
        }
        __syncthreads();
#pragma unroll
        for (int kc = 0; kc < 2; ++kc) {
            const int blk = kc * 4 + g;
            half8 a_hi[2], a_lo[2], b_hi[4], b_lo[4];
#pragma unroll
            for (int mf = 0; mf < 2; ++mf) {
                int row = w * 32 + mf * 16 + n15;
                int el = row * 64 + ((blk ^ (row & 7)) * 8);
                a_hi[mf] = *reinterpret_cast<const half8*>(&AhiS[el]);
                a_lo[mf] = *reinterpret_cast<const half8*>(&AloS[el]);
            }
#pragma unroll
            for (int nt = 0; nt < 4; ++nt) {
                int row = nt * 16 + n15;
                int el = row * 64 + ((blk ^ (row & 7)) * 8);
                b_hi[nt] = *reinterpret_cast<const half8*>(&WhiS[el]);
                b_lo[nt] = *reinterpret_cast<const half8*>(&WloS[el]);
            }
#pragma unroll
            for (int mf = 0; mf < 2; ++mf)
#pragma unroll
                for (int nt = 0; nt < 4; ++nt) {
                    acc_hi[mf][nt] = MFMA16(a_hi[mf], b_hi[nt], acc_hi[mf][nt]);
                    acc_lo[mf][nt] = MFMA16(a_hi[mf], b_lo[nt], acc_lo[mf][nt]);
                    acc_lo[mf][nt] = MFMA16(a_lo[mf], b_hi[nt], acc_lo[mf][nt]);
                }
        }
    }
#pragma unroll
    for (int nt = 0; nt < 4; ++nt) {
        int col = bn + nt * 16 + n15;
        float bc = bias[col];
#pragma unroll
        for (int mf = 0; mf < 2; ++mf)
#pragma unroll
            for (int r = 0; r < 4; ++r) {
                size_t row = bm + w * 32 + mf * 16 + g * 4 + r;
                float y = acc_hi[mf][nt][r] + acc_lo[mf][nt][r] * (1.0f / 256.0f) + bc;
                if (!isV) {
                    _Float16 h = (_Float16)y;
                    Khi[row * CC + col] = h;
                    Klo[row * CC + col] = (_Float16)((y - (float)h) * 256.0f);
                } else {
                    Vt[((row >> 10) * CC + col) * NKK + (row & 1023)] = (_Float16)y;
                }
            }
    }
}

// ---------------------------------------------------------------------------
// Fused: depthwise 2x2/2 conv + LayerNorm (blocks 0..4095) writing f16 pair,
// PLUS weight pre-split (blocks 4096..5247). One launch, 128 threads each.
// ---------------------------------------------------------------------------
__global__ __launch_bounds__(128)
void srconv_splitw(const float* __restrict__ x, const float* __restrict__ srw,
                   const float* __restrict__ srb, const float* __restrict__ g,
                   const float* __restrict__ beta,
                   _Float16* __restrict__ xrh, _Float16* __restrict__ xrl,
                   const float* __restrict__ Wq, const float* __restrict__ Wk,
                   const float* __restrict__ Wv, const float* __restrict__ Wp,
                   _Float16* __restrict__ wqh, _Float16* __restrict__ wql,
                   _Float16* __restrict__ wkh, _Float16* __restrict__ wkl,
                   _Float16* __restrict__ wvh, _Float16* __restrict__ wvl,
                   _Float16* __restrict__ wph) {
    const int bid = blockIdx.x;
    const int tid = threadIdx.x;
    if (bid >= BB * NKK) {
        // ---- weight pre-split: 1152 blocks x 128 threads = 147456
        int i = (bid - BB * NKK) * 128 + tid;
        float q = Wq[i], k = Wk[i], v = Wv[i], p = Wp[i];
        _Float16 h;
        h = (_Float16)q; wqh[i] = h; wql[i] = (_Float16)((q - (float)h) * 256.0f);
        h = (_Float16)k; wkh[i] = h; wkl[i] = (_Float16)((k - (float)h) * 256.0f);
        h = (_Float16)v; wvh[i] = h; wvl[i] = (_Float16)((v - (float)h) * 256.0f);
        wph[i] = (_Float16)p;
        return;
    }
    const int row = bid;
    const int b  = row >> 10;
    const int nk = row & 1023;
    const int oy = nk >> 5;
    const int ox = nk & 31;
    const int n0 = (2 * oy) * 64 + 2 * ox;
    const float* xb = x + ((size_t)b * NN + n0) * CC;

    float vals[3];
    float lsum = 0.f, lsum2 = 0.f;
#pragma unroll
    for (int i = 0; i < 3; ++i) {
        const int c = tid + i * 128;
        const float4 w = *reinterpret_cast<const float4*>(srw + (size_t)c * 4);
        float v = xb[c] * w.x + xb[CC + c] * w.y +
                  xb[(size_t)64 * CC + c] * w.z + xb[(size_t)65 * CC + c] * w.w + srb[c];
        vals[i] = v;
        lsum += v;
        lsum2 += v * v;
    }
#pragma unroll
    for (int off = 32; off; off >>= 1) {
        lsum  += __shfl_down(lsum, off);
        lsum2 += __shfl_down(lsum2, off);
    }
    __shared__ float ssum[2], ssum2[2];
    if ((tid & 63) == 0) { ssum[tid >> 6] = lsum; ssum2[tid >> 6] = lsum2; }
    __syncthreads();
    const float tot  = ssum[0] + ssum[1];
    const float tot2 = ssum2[0] + ssum2[1];
    const float mu  = tot * (1.0f / 384.0f);
    const float var = tot2 * (1.0f / 384.0f) - mu * mu;
    const float rstd = 1.0f / sqrtf(var + LN_EPS);

    _Float16* oh = xrh + (size_t)row * CC;
    _Float16* ol = xrl + (size_t)row * CC;
#pragma unroll
    for (int i = 0; i < 3; ++i) {
        const int c = tid + i * 128;
        float v = (vals[i] - mu) * rstd * g[c] + beta[c];
        _Float16 h = (_Float16)v;
        oh[c] = h;
        ol[c] = (_Float16)((v - (float)h) * 256.0f);
    }
}

// ---------------------------------------------------------------------------
// Fused MFMA attention, neg-softmax, m == 0 (linear accumulation).
// v9: same shape as v8 (QT=128, 4 waves x 32 q-rows, KVBLK=32, 3 blocks/CU)
// with bank-conflict-free V/P swizzle: sw(d) = (d>>1)&3 puts the 8 start
// banks at 16*(d&1)+4*((d>>1)&3) per 16-lane phase -> 2-way (free) instead
// of the 4-way conflicts of sw(d)=d&3. kt loop manually 2x-unrolled so all
// LDS addresses are loop-invariant.
// ---------------------------------------------------------------------------
__global__ __launch_bounds__(256, 3)
void attn_mfma(const _Float16* __restrict__ Qhi, const _Float16* __restrict__ Qlo,
               const _Float16* __restrict__ Khi, const _Float16* __restrict__ Klo,
               const _Float16* __restrict__ Vt, _Float16* __restrict__ O)
{
    __shared__ _Float16 KhiS[2][32 * 64];   // [key][d]
    __shared__ _Float16 KloS[2][32 * 64];
    __shared__ _Float16 VTS[2][64 * 32];    // [d][key]
    __shared__ _Float16 PWS[4][1024];       // per-wave: 2 frags x [16 q][32 key]

    const int tid = threadIdx.x;
    const int w = tid >> 6, lane = tid & 63;
    const int g = lane >> 4, q15 = lane & 15;
    _Float16* PW = PWS[w];

    const int qt = blockIdx.x, h = blockIdx.y, b = blockIdx.z;

    // ---- Q B-fragments: 2 frags (rows qt*128 + w*32 + f*16 + q15)
    half8 qh[2][2], ql[2][2];
    {
        size_t qoff = ((size_t)b * NN + qt * 128 + w * 32 + q15) * CC + h * 64 + g * 8;
#pragma unroll
        for (int f = 0; f < 2; ++f) {
            qh[f][0] = *reinterpret_cast<const half8*>(Qhi + qoff + f * 16 * CC);
            qh[f][1] = *reinterpret_cast<const half8*>(Qhi + qoff + f * 16 * CC + 32);
            ql[f][0] = *reinterpret_cast<const half8*>(Qlo + qoff + f * 16 * CC);
            ql[f][1] = *reinterpret_cast<const half8*>(Qlo + qoff + f * 16 * CC + 32);
        }
    }
    // drain Q loads so the loop's vmcnt counts only track staging
    asm volatile("s_waitcnt vmcnt(0)" ::: "memory");

    // ---- staging geometry: K tiles [32 key][64 d]: key=tid>>3, d-blk=tid&7,
    // sw_k(key)=key&7. V tile [64 d][32 key]: d=tid>>2, key-blk=tid&3,
    // sw_v(d)=(d>>1)&3. Inverse-swizzled global source, linear LDS dest.
    const int krow = tid >> 3, kdg = tid & 7;
    const int kscol = (kdg ^ (krow & 7)) * 8;
    const _Float16* ksrc = Khi + ((size_t)b * NKK + krow) * CC + h * 64 + kscol;
    const _Float16* lsrc = Klo + ((size_t)b * NKK + krow) * CC + h * 64 + kscol;
    const int vd = tid >> 2, vkb = tid & 3;
    const _Float16* vsrc = Vt + ((size_t)b * CC + h * 64 + vd) * NKK + ((vkb ^ ((vd >> 1) & 3)) * 8);

    f32x4 zero4 = {0.f, 0.f, 0.f, 0.f};
    f32x4 o[2][4];
#pragma unroll
    for (int f = 0; f < 2; ++f)
#pragma unroll
        for (int nt = 0; nt < 4; ++nt) o[f][nt] = zero4;
    float l[2] = {0.f, 0.f};

#define ISSUE(kt, buf)                                                        \
    {                                                                         \
        GLL16(ksrc + (size_t)(kt) * 32 * CC, &KhiS[buf][tid * 8]);            \
        GLL16(lsrc + (size_t)(kt) * 32 * CC, &KloS[buf][tid * 8]);            \
        GLL16(vsrc + (kt) * 32,              &VTS[buf][tid * 8]);             \
    }

    auto COMPUTE = [&](const _Float16* KH, const _Float16* KL, const _Float16* VT) {
        float ls[2] = {0.f, 0.f};
        // ---- QK^T + softmax (shared ah/al reads feed both frags)
#pragma unroll
        for (int mt = 0; mt < 2; ++mt) {
            f32x4 sh[2], sl[2];
#pragma unroll
            for (int f = 0; f < 2; ++f) { sh[f] = zero4; sl[f] = zero4; }
            __builtin_amdgcn_s_setprio(1);
#pragma unroll
            for (int kc = 0; kc < 2; ++kc) {
                int key = mt * 16 + q15;
                int el = key * 64 + (((kc * 4 + g) ^ (key & 7)) * 8);
                half8 ah = *reinterpret_cast<const half8*>(&KH[el]);
                half8 al = *reinterpret_cast<const half8*>(&KL[el]);
#pragma unroll
                for (int f = 0; f < 2; ++f) {
                    sh[f] = MFMA16(ah, qh[f][kc], sh[f]);
                    sl[f] = MFMA16(ah, ql[f][kc], sl[f]);
                    sl[f] = MFMA16(al, qh[f][kc], sl[f]);
                }
            }
            __builtin_amdgcn_s_setprio(0);
            // P write: logical keys mt*16 + g*4..+3 -> physical blk ^ sw(q15)
            int elw = q15 * 32 + (((mt * 2 + (g >> 1)) ^ ((q15 >> 1) & 3)) * 8) + (g & 1) * 4;
#pragma unroll
            for (int f = 0; f < 2; ++f) {
                half4v pk;
#pragma unroll
                for (int r = 0; r < 4; ++r) {
                    float sv = sh[f][r] + sl[f][r] * (1.0f / 256.0f);
                    float e = __expf(fabsf(sv));
                    ls[f] += e;
                    pk[r] = (_Float16)__builtin_copysignf(e, sv);
                }
                *reinterpret_cast<half4v*>(&PW[elw + f * 512]) = pk;
            }
        }
#pragma unroll
        for (int f = 0; f < 2; ++f) {
            ls[f] += __shfl_xor(ls[f], 16);
            ls[f] += __shfl_xor(ls[f], 32);
            l[f] += ls[f];
        }

        // ---- PV: O[q][d] += P[q][key] * V[key][d]  (vb shared by both frags)
        __builtin_amdgcn_s_setprio(1);
        {
            int pel = q15 * 32 + ((g ^ ((q15 >> 1) & 3)) * 8);
            half8 pa0 = *reinterpret_cast<const half8*>(&PW[pel]);
            half8 pa1 = *reinterpret_cast<const half8*>(&PW[pel + 512]);
#pragma unroll
            for (int nt = 0; nt < 4; ++nt) {
                int d = nt * 16 + q15;
                int vel = d * 32 + ((g ^ ((d >> 1) & 3)) * 8);
                half8 vb = *reinterpret_cast<const half8*>(&VT[vel]);
                o[0][nt] = MFMA16(pa0, vb, o[0][nt]);
                o[1][nt] = MFMA16(pa1, vb, o[1][nt]);
            }
        }
        __builtin_amdgcn_s_setprio(0);
    };

    ISSUE(0, 0);

#pragma unroll 1
    for (int kt2 = 0; kt2 < 32; kt2 += 2) {
        // ---- half A: compute buf0, prefetch kt2+1 -> buf1
        ISSUE(kt2 + 1, 1);
        asm volatile("s_waitcnt vmcnt(3)" ::: "memory");
        __builtin_amdgcn_s_barrier();
        COMPUTE(KhiS[0], KloS[0], VTS[0]);
        asm volatile("" ::: "memory");
        __builtin_amdgcn_s_barrier();

        // ---- half B: compute buf1, prefetch kt2+2 -> buf0
        if (kt2 + 2 < 32) {
            ISSUE(kt2 + 2, 0);
            asm volatile("s_waitcnt vmcnt(3)" ::: "memory");
        } else {
            asm volatile("s_waitcnt vmcnt(0)" ::: "memory");
        }
        __builtin_amdgcn_s_barrier();
        COMPUTE(KhiS[1], KloS[1], VTS[1]);
        asm volatile("" ::: "memory");
        __builtin_amdgcn_s_barrier();
    }
#undef ISSUE

    // ---- epilogue: O[q][d] / l  (O aliases Qlo: consumed above, unique owner)
#pragma unroll
    for (int f = 0; f < 2; ++f) {
        float rl = 1.0f / l[f];
        float rlq[4];
#pragma unroll
        for (int r = 0; r < 4; ++r) rlq[r] = __shfl(rl, g * 4 + r);
#pragma unroll
        for (int nt = 0; nt < 4; ++nt)
#pragma unroll
            for (int r = 0; r < 4; ++r) {
                size_t row = (size_t)b * NN + qt * 128 + w * 32 + f * 16 + g * 4 + r;
                O[row * CC + h * 64 + nt * 16 + q15] = (_Float16)(o[f][nt][r] * rlq[r]);
            }
    }
}

// ---------------------------------------------------------------------------
extern "C" void kernel_launch(void* const* d_in, const int* in_sizes, int n_in,
                              void* d_out, int out_size, void* d_ws, size_t ws_size,
                              hipStream_t stream) {
    const float* x   = (const float*)d_in[0];
    const float* Wq  = (const float*)d_in[1];
    const float* bq  = (const float*)d_in[2];
    const float* Wk  = (const float*)d_in[3];
    const float* bk  = (const float*)d_in[4];
    const float* Wv  = (const float*)d_in[5];
    const float* bv  = (const float*)d_in[6];
    const float* srw = (const float*)d_in[7];
    const float* srb = (const float*)d_in[8];
    const float* lng = (const float*)d_in[9];
    const float* lnb = (const float*)d_in[10];
    const float* Wp  = (const float*)d_in[11];
    const float* bp  = (const float*)d_in[12];
    float* out = (float*)d_out;

    // workspace layout (~43 MB)
    char* wsb = (char*)d_ws;
    _Float16* Qhi  = (_Float16*)wsb;                   // 12.58 MB
    _Float16* Qlo  = (_Float16*)(wsb + 12582912);      // 12.58 MB (also attn O)
    _Float16* XRhi = (_Float16*)(wsb + 25165824);      // 3.15 MB
    _Float16* XRlo = (_Float16*)(wsb + 28311552);      // 3.15 MB
    _Float16* Khi  = (_Float16*)(wsb + 31457280);      // 3.15 MB
    _Float16* Klo  = (_Float16*)(wsb + 34603008);      // 3.15 MB
    _Float16* Vt   = (_Float16*)(wsb + 37748736);      // 3.15 MB [b][c][nk]
    _Float16* Wqh  = (_Float16*)(wsb + 40894464);      // 7 x 0.295 MB
    _Float16* Wql  = Wqh + 147456;
    _Float16* Wkh  = Wql + 147456;
    _Float16* Wkl  = Wkh + 147456;
    _Float16* Wvh  = Wkl + 147456;
    _Float16* Wvl  = Wvh + 147456;
    _Float16* Wph  = Wvl + 147456;
    _Float16* Ob   = Qlo;

    // conv + LN -> pre-split pair, fused with weight pre-split (one launch)
    srconv_splitw<<<dim3(BB * NKK + 1152), dim3(128), 0, stream>>>(
        x, srw, srb, lng, lnb, XRhi, XRlo,
        Wq, Wk, Wv, Wp, Wqh, Wql, Wkh, Wkl, Wvh, Wvl, Wph);
    // Q projection: (x @ Wq^T + bq) * 0.125, split pair out
    gemm_mf<0, 1, 0><<<dim3(128, 6), 256, 0, stream>>>(
        x, nullptr, Wqh, Wql, bq, Qhi, Qlo, nullptr, 0.125f);
    // fused K + V projections (z = 0: K pair, z = 1: V transposed)
    gemm_kv<<<dim3(32, 6, 2), 256, 0, stream>>>(
        XRhi, XRlo, Wkh, Wkl, Wvh, Wvl, bk, bv, Khi, Klo, Vt);
    // fused attention (128 q rows per block, 4 waves x 32 rows, 3 blocks/CU)
    attn_mfma<<<dim3(32, 6, 4), 256, 0, stream>>>(Qhi, Qlo, Khi, Klo, Vt, Ob);
    // output projection -> d_out (f32)
    gemm_mf<2, 2, 2><<<dim3(128, 6), 256, 0, stream>>>(
        Ob, nullptr, Wph, nullptr, bp, nullptr, nullptr, out, 1.0f);
}

// Round 10
// 125.225 us; speedup vs baseline: 1.1829x; 1.0331x over previous
//
#include <hip/hip_runtime.h>
#include <hip/hip_bf16.h>
#include <math.h>

#define BB 4
#define NN 4096
#define CC 384
#define NHH 6
#define HDD 64
#define NKK 1024
#define LN_EPS 1e-5f

typedef _Float16 half8 __attribute__((ext_vector_type(8)));
typedef _Float16 half4v __attribute__((ext_vector_type(4)));
typedef _Float16 half2v __attribute__((ext_vector_type(2)));
typedef float f32x4 __attribute__((ext_vector_type(4)));

#define MFMA16(a, b, c) __builtin_amdgcn_mfma_f32_16x16x32_f16((a), (b), (c), 0, 0, 0)

#define GLL16(src, dst)                                                       \
    __builtin_amdgcn_global_load_lds(                                         \
        (const __attribute__((address_space(1))) void*)(src),                 \
        (__attribute__((address_space(3))) void*)(dst), 16, 0, 0)

// ---------------------------------------------------------------------------
// Out-projection GEMM (f16 A, f16 W, f32 out) — gemm_mf<2,2,2> of round 9.
// ---------------------------------------------------------------------------
__global__ __launch_bounds__(256) void gemm_out(
    const _Float16* __restrict__ A, const _Float16* __restrict__ Whi,
    const float* __restrict__ bias, float* __restrict__ Yf)
{
    __shared__ _Float16 AhiS[128 * 64];
    __shared__ _Float16 WhiS[64 * 64];

    const int tid = threadIdx.x;
    const int bm = blockIdx.x * 128;
    const int bn = blockIdx.y * 64;
    const int w = tid >> 6, lane = tid & 63;
    const int g = lane >> 4, n15 = lane & 15;

    f32x4 zero4 = {0.f, 0.f, 0.f, 0.f};
    f32x4 acc[2][4];
#pragma unroll
    for (int mf = 0; mf < 2; ++mf)
#pragma unroll
        for (int nt = 0; nt < 4; ++nt) acc[mf][nt] = zero4;

    for (int k0 = 0; k0 < CC; k0 += 64) {
        __syncthreads();
#pragma unroll
        for (int i = 0; i < 4; ++i) {
            int id = tid + 256 * i;
            int row = id >> 3, dg = id & 7;
            half8 av = *reinterpret_cast<const half8*>(A + (size_t)(bm + row) * CC + k0 + dg * 8);
            int el = row * 64 + ((dg ^ (row & 7)) * 8);
            *reinterpret_cast<half8*>(&AhiS[el]) = av;
        }
#pragma unroll
        for (int i = 0; i < 2; ++i) {
            int id = tid + 256 * i;
            int row = id >> 3, dg = id & 7;
            half8 wh = *reinterpret_cast<const half8*>(Whi + (size_t)(bn + row) * CC + k0 + dg * 8);
            int el = row * 64 + ((dg ^ (row & 7)) * 8);
            *reinterpret_cast<half8*>(&WhiS[el]) = wh;
        }
        __syncthreads();
#pragma unroll
        for (int kc = 0; kc < 2; ++kc) {
            const int blk = kc * 4 + g;
            half8 a_hi[2], b_hi[4];
#pragma unroll
            for (int mf = 0; mf < 2; ++mf) {
                int row = w * 32 + mf * 16 + n15;
                a_hi[mf] = *reinterpret_cast<const half8*>(&AhiS[row * 64 + ((blk ^ (row & 7)) * 8)]);
            }
#pragma unroll
            for (int nt = 0; nt < 4; ++nt) {
                int row = nt * 16 + n15;
                b_hi[nt] = *reinterpret_cast<const half8*>(&WhiS[row * 64 + ((blk ^ (row & 7)) * 8)]);
            }
#pragma unroll
            for (int mf = 0; mf < 2; ++mf)
#pragma unroll
                for (int nt = 0; nt < 4; ++nt)
                    acc[mf][nt] = MFMA16(a_hi[mf], b_hi[nt], acc[mf][nt]);
        }
    }
#pragma unroll
    for (int nt = 0; nt < 4; ++nt) {
        int col = bn + nt * 16 + n15;
        float bc = bias[col];
#pragma unroll
        for (int mf = 0; mf < 2; ++mf)
#pragma unroll
            for (int r = 0; r < 4; ++r) {
                size_t row = bm + w * 32 + mf * 16 + g * 4 + r;
                Yf[row * CC + col] = acc[mf][nt][r] + bc;
            }
    }
}

// ---------------------------------------------------------------------------
// Fused Q + K + V projections, one launch (runtime mode by blockIdx.x).
// Q (blocks 0..767):   A = x (f32, split on stage), Y = (xWq^T+bq)*0.125 pair
// K (blocks 768..959): A = XR pair, Y = K pair
// V (blocks 960..1151):A = XR pair, Y = V transposed Vt[b][c][nk]
// All: BM=128, BN=64, BK=64, 3-MFMA split, swizzled LDS (round-9-proven).
// ---------------------------------------------------------------------------
__global__ __launch_bounds__(256) void proj_all(
    const float* __restrict__ x,
    const _Float16* __restrict__ XRh, const _Float16* __restrict__ XRl,
    const _Float16* __restrict__ Wqh, const _Float16* __restrict__ Wql,
    const _Float16* __restrict__ Wkh, const _Float16* __restrict__ Wkl,
    const _Float16* __restrict__ Wvh, const _Float16* __restrict__ Wvl,
    const float* __restrict__ bq, const float* __restrict__ bk,
    const float* __restrict__ bv,
    _Float16* __restrict__ Qhi, _Float16* __restrict__ Qlo,
    _Float16* __restrict__ Khi, _Float16* __restrict__ Klo,
    _Float16* __restrict__ Vt)
{
    __shared__ _Float16 AhiS[128 * 64];
    __shared__ _Float16 AloS[128 * 64];
    __shared__ _Float16 WhiS[64 * 64];
    __shared__ _Float16 WloS[64 * 64];

    const int bid = blockIdx.x;
    const int tid = threadIdx.x;
    int bm, bn, mode;                 // 0 = Q, 1 = K, 2 = V
    if (bid < 768) {
        bm = (bid & 127) * 128; bn = (bid >> 7) * 64; mode = 0;
    } else {
        int idx = bid - 768;
        bm = (idx & 31) * 128; bn = ((idx >> 5) % 6) * 64;
        mode = (idx >= 192) ? 2 : 1;
    }
    const _Float16* Whi = (mode == 0) ? Wqh : ((mode == 1) ? Wkh : Wvh);
    const _Float16* Wlo = (mode == 0) ? Wql : ((mode == 1) ? Wkl : Wvl);
    const float* bias   = (mode == 0) ? bq  : ((mode == 1) ? bk  : bv);
    const float scale   = (mode == 0) ? 0.125f : 1.0f;

    const int w = tid >> 6, lane = tid & 63;
    const int g = lane >> 4, n15 = lane & 15;

    f32x4 zero4 = {0.f, 0.f, 0.f, 0.f};
    f32x4 acc_hi[2][4], acc_lo[2][4];
#pragma unroll
    for (int mf = 0; mf < 2; ++mf)
#pragma unroll
        for (int nt = 0; nt < 4; ++nt) { acc_hi[mf][nt] = zero4; acc_lo[mf][nt] = zero4; }

    for (int k0 = 0; k0 < CC; k0 += 64) {
        __syncthreads();
        if (mode == 0) {
            // A = x, fp32 split on stage
#pragma unroll
            for (int i = 0; i < 8; ++i) {
                int id = tid + 256 * i;
                int row = id >> 4, c4 = (id & 15) * 4;
                float4 av = *reinterpret_cast<const float4*>(x + (size_t)(bm + row) * CC + k0 + c4);
                int el = row * 64 + (((c4 >> 3) ^ (row & 7)) * 8) + (c4 & 7);
                float vv[4] = {av.x, av.y, av.z, av.w};
                half4v hi, lo;
#pragma unroll
                for (int e = 0; e < 4; ++e) {
                    _Float16 h = (_Float16)vv[e];
                    hi[e] = h;
                    lo[e] = (_Float16)((vv[e] - (float)h) * 256.0f);
                }
                *reinterpret_cast<half4v*>(&AhiS[el]) = hi;
                *reinterpret_cast<half4v*>(&AloS[el]) = lo;
            }
        } else {
            // A = XR pre-split pair
#pragma unroll
            for (int i = 0; i < 4; ++i) {
                int id = tid + 256 * i;
                int row = id >> 3, dg = id & 7;
                size_t go = (size_t)(bm + row) * CC + k0 + dg * 8;
                half8 hv = *reinterpret_cast<const half8*>(XRh + go);
                half8 lv = *reinterpret_cast<const half8*>(XRl + go);
                int el = row * 64 + ((dg ^ (row & 7)) * 8);
                *reinterpret_cast<half8*>(&AhiS[el]) = hv;
                *reinterpret_cast<half8*>(&AloS[el]) = lv;
            }
        }
#pragma unroll
        for (int i = 0; i < 2; ++i) {
            int id = tid + 256 * i;
            int row = id >> 3, dg = id & 7;
            size_t go = (size_t)(bn + row) * CC + k0 + dg * 8;
            half8 wh = *reinterpret_cast<const half8*>(Whi + go);
            half8 wl = *reinterpret_cast<const half8*>(Wlo + go);
            int el = row * 64 + ((dg ^ (row & 7)) * 8);
            *reinterpret_cast<half8*>(&WhiS[el]) = wh;
            *reinterpret_cast<half8*>(&WloS[el]) = wl;
        }
        __syncthreads();
#pragma unroll
        for (int kc = 0; kc < 2; ++kc) {
            const int blk = kc * 4 + g;
            half8 a_hi[2], a_lo[2], b_hi[4], b_lo[4];
#pragma unroll
            for (int mf = 0; mf < 2; ++mf) {
                int row = w * 32 + mf * 16 + n15;
                int el = row * 64 + ((blk ^ (row & 7)) * 8);
                a_hi[mf] = *reinterpret_cast<const half8*>(&AhiS[el]);
                a_lo[mf] = *reinterpret_cast<const half8*>(&AloS[el]);
            }
#pragma unroll
            for (int nt = 0; nt < 4; ++nt) {
                int row = nt * 16 + n15;
                int el = row * 64 + ((blk ^ (row & 7)) * 8);
                b_hi[nt] = *reinterpret_cast<const half8*>(&WhiS[el]);
                b_lo[nt] = *reinterpret_cast<const half8*>(&WloS[el]);
            }
#pragma unroll
            for (int mf = 0; mf < 2; ++mf)
#pragma unroll
                for (int nt = 0; nt < 4; ++nt) {
                    acc_hi[mf][nt] = MFMA16(a_hi[mf], b_hi[nt], acc_hi[mf][nt]);
                    acc_lo[mf][nt] = MFMA16(a_hi[mf], b_lo[nt], acc_lo[mf][nt]);
                    acc_lo[mf][nt] = MFMA16(a_lo[mf], b_hi[nt], acc_lo[mf][nt]);
                }
        }
    }
#pragma unroll
    for (int nt = 0; nt < 4; ++nt) {
        int col = bn + nt * 16 + n15;
        float bc = bias[col];
#pragma unroll
        for (int mf = 0; mf < 2; ++mf)
#pragma unroll
            for (int r = 0; r < 4; ++r) {
                size_t row = bm + w * 32 + mf * 16 + g * 4 + r;
                float y = (acc_hi[mf][nt][r] + acc_lo[mf][nt][r] * (1.0f / 256.0f) + bc) * scale;
                if (mode == 0) {
                    _Float16 h = (_Float16)y;
                    Qhi[row * CC + col] = h;
                    Qlo[row * CC + col] = (_Float16)((y - (float)h) * 256.0f);
                } else if (mode == 1) {
                    _Float16 h = (_Float16)y;
                    Khi[row * CC + col] = h;
                    Klo[row * CC + col] = (_Float16)((y - (float)h) * 256.0f);
                } else {
                    Vt[((row >> 10) * CC + col) * NKK + (row & 1023)] = (_Float16)y;
                }
            }
    }
}

// ---------------------------------------------------------------------------
// Fused: depthwise 2x2/2 conv + LayerNorm (blocks 0..4095) writing f16 pair,
// PLUS weight pre-split (blocks 4096..5247). One launch, 128 threads each.
// ---------------------------------------------------------------------------
__global__ __launch_bounds__(128)
void srconv_splitw(const float* __restrict__ x, const float* __restrict__ srw,
                   const float* __restrict__ srb, const float* __restrict__ g,
                   const float* __restrict__ beta,
                   _Float16* __restrict__ xrh, _Float16* __restrict__ xrl,
                   const float* __restrict__ Wq, const float* __restrict__ Wk,
                   const float* __restrict__ Wv, const float* __restrict__ Wp,
                   _Float16* __restrict__ wqh, _Float16* __restrict__ wql,
                   _Float16* __restrict__ wkh, _Float16* __restrict__ wkl,
                   _Float16* __restrict__ wvh, _Float16* __restrict__ wvl,
                   _Float16* __restrict__ wph) {
    const int bid = blockIdx.x;
    const int tid = threadIdx.x;
    if (bid >= BB * NKK) {
        int i = (bid - BB * NKK) * 128 + tid;
        float q = Wq[i], k = Wk[i], v = Wv[i], p = Wp[i];
        _Float16 h;
        h = (_Float16)q; wqh[i] = h; wql[i] = (_Float16)((q - (float)h) * 256.0f);
        h = (_Float16)k; wkh[i] = h; wkl[i] = (_Float16)((k - (float)h) * 256.0f);
        h = (_Float16)v; wvh[i] = h; wvl[i] = (_Float16)((v - (float)h) * 256.0f);
        wph[i] = (_Float16)p;
        return;
    }
    const int row = bid;
    const int b  = row >> 10;
    const int nk = row & 1023;
    const int oy = nk >> 5;
    const int ox = nk & 31;
    const int n0 = (2 * oy) * 64 + 2 * ox;
    const float* xb = x + ((size_t)b * NN + n0) * CC;

    float vals[3];
    float lsum = 0.f, lsum2 = 0.f;
#pragma unroll
    for (int i = 0; i < 3; ++i) {
        const int c = tid + i * 128;
        const float4 w = *reinterpret_cast<const float4*>(srw + (size_t)c * 4);
        float v = xb[c] * w.x + xb[CC + c] * w.y +
                  xb[(size_t)64 * CC + c] * w.z + xb[(size_t)65 * CC + c] * w.w + srb[c];
        vals[i] = v;
        lsum += v;
        lsum2 += v * v;
    }
#pragma unroll
    for (int off = 32; off; off >>= 1) {
        lsum  += __shfl_down(lsum, off);
        lsum2 += __shfl_down(lsum2, off);
    }
    __shared__ float ssum[2], ssum2[2];
    if ((tid & 63) == 0) { ssum[tid >> 6] = lsum; ssum2[tid >> 6] = lsum2; }
    __syncthreads();
    const float tot  = ssum[0] + ssum[1];
    const float tot2 = ssum2[0] + ssum2[1];
    const float mu  = tot * (1.0f / 384.0f);
    const float var = tot2 * (1.0f / 384.0f) - mu * mu;
    const float rstd = 1.0f / sqrtf(var + LN_EPS);

    _Float16* oh = xrh + (size_t)row * CC;
    _Float16* ol = xrl + (size_t)row * CC;
#pragma unroll
    for (int i = 0; i < 3; ++i) {
        const int c = tid + i * 128;
        float v = (vals[i] - mu) * rstd * g[c] + beta[c];
        _Float16 h = (_Float16)v;
        oh[c] = h;
        ol[c] = (_Float16)((v - (float)h) * 256.0f);
    }
}

// ---------------------------------------------------------------------------
// Fused MFMA attention, neg-softmax, m == 0 (linear accumulation).
// v10: triple-buffered K/V with ONE barrier per kt. ISSUE(kt+2) placed after
// COMPUTE(kt): it targets buf[(kt+2)%3] = buf[(kt-1)%3], last read at kt-1,
// and all waves passed barrier(kt) after finishing COMPUTE(kt-1) -> no race.
// vmcnt(3) waits tile kt (2 tiles = 6 loads in flight, issued ~2 compute
// phases earlier -> latency fully hidden). LDS 44 KB -> 3 blocks/CU.
// Softmax l-reduction deferred to epilogue (sum is linear).
// ---------------------------------------------------------------------------
__global__ __launch_bounds__(256, 3)
void attn_mfma(const _Float16* __restrict__ Qhi, const _Float16* __restrict__ Qlo,
               const _Float16* __restrict__ Khi, const _Float16* __restrict__ Klo,
               const _Float16* __restrict__ Vt, _Float16* __restrict__ O)
{
    __shared__ _Float16 KhiS[3][32 * 64];   // [key][d]
    __shared__ _Float16 KloS[3][32 * 64];
    __shared__ _Float16 VTS[3][64 * 32];    // [d][key]
    __shared__ _Float16 PWS[4][1024];       // per-wave: 2 frags x [16 q][32 key]

    const int tid = threadIdx.x;
    const int w = tid >> 6, lane = tid & 63;
    const int g = lane >> 4, q15 = lane & 15;
    _Float16* PW = PWS[w];

    const int qt = blockIdx.x, h = blockIdx.y, b = blockIdx.z;

    // ---- Q B-fragments: 2 frags (rows qt*128 + w*32 + f*16 + q15)
    half8 qh[2][2], ql[2][2];
    {
        size_t qoff = ((size_t)b * NN + qt * 128 + w * 32 + q15) * CC + h * 64 + g * 8;
#pragma unroll
        for (int f = 0; f < 2; ++f) {
            qh[f][0] = *reinterpret_cast<const half8*>(Qhi + qoff + f * 16 * CC);
            qh[f][1] = *reinterpret_cast<const half8*>(Qhi + qoff + f * 16 * CC + 32);
            ql[f][0] = *reinterpret_cast<const half8*>(Qlo + qoff + f * 16 * CC);
            ql[f][1] = *reinterpret_cast<const half8*>(Qlo + qoff + f * 16 * CC + 32);
        }
    }
    // drain Q loads so the loop's vmcnt counts only track staging
    asm volatile("s_waitcnt vmcnt(0)" ::: "memory");

    // ---- staging geometry: K tiles [32 key][64 d]: key=tid>>3, d-blk=tid&7,
    // sw_k(key)=key&7. V tile [64 d][32 key]: d=tid>>2, key-blk=tid&3,
    // sw_v(d)=(d>>1)&3. Inverse-swizzled global source, linear LDS dest.
    const int krow = tid >> 3, kdg = tid & 7;
    const int kscol = (kdg ^ (krow & 7)) * 8;
    const _Float16* ksrc = Khi + ((size_t)b * NKK + krow) * CC + h * 64 + kscol;
    const _Float16* lsrc = Klo + ((size_t)b * NKK + krow) * CC + h * 64 + kscol;
    const int vd = tid >> 2, vkb = tid & 3;
    const _Float16* vsrc = Vt + ((size_t)b * CC + h * 64 + vd) * NKK + ((vkb ^ ((vd >> 1) & 3)) * 8);

    f32x4 zero4 = {0.f, 0.f, 0.f, 0.f};
    f32x4 o[2][4];
#pragma unroll
    for (int f = 0; f < 2; ++f)
#pragma unroll
        for (int nt = 0; nt < 4; ++nt) o[f][nt] = zero4;
    float l[2] = {0.f, 0.f};

#define ISSUE(kt, buf)                                                        \
    {                                                                         \
        GLL16(ksrc + (size_t)(kt) * 32 * CC, &KhiS[buf][tid * 8]);            \
        GLL16(lsrc + (size_t)(kt) * 32 * CC, &KloS[buf][tid * 8]);            \
        GLL16(vsrc + (kt) * 32,              &VTS[buf][tid * 8]);             \
    }

    auto COMPUTE = [&](const _Float16* KH, const _Float16* KL, const _Float16* VT) {
        // ---- QK^T + softmax (shared ah/al reads feed both frags)
#pragma unroll
        for (int mt = 0; mt < 2; ++mt) {
            f32x4 sh[2], sl[2];
#pragma unroll
            for (int f = 0; f < 2; ++f) { sh[f] = zero4; sl[f] = zero4; }
            __builtin_amdgcn_s_setprio(1);
#pragma unroll
            for (int kc = 0; kc < 2; ++kc) {
                int key = mt * 16 + q15;
                int el = key * 64 + (((kc * 4 + g) ^ (key & 7)) * 8);
                half8 ah = *reinterpret_cast<const half8*>(&KH[el]);
                half8 al = *reinterpret_cast<const half8*>(&KL[el]);
#pragma unroll
                for (int f = 0; f < 2; ++f) {
                    sh[f] = MFMA16(ah, qh[f][kc], sh[f]);
                    sl[f] = MFMA16(ah, ql[f][kc], sl[f]);
                    sl[f] = MFMA16(al, qh[f][kc], sl[f]);
                }
            }
            __builtin_amdgcn_s_setprio(0);
            int elw = q15 * 32 + (((mt * 2 + (g >> 1)) ^ ((q15 >> 1) & 3)) * 8) + (g & 1) * 4;
#pragma unroll
            for (int f = 0; f < 2; ++f) {
                half4v pk;
#pragma unroll
                for (int r = 0; r < 4; ++r) {
                    float sv = sh[f][r] + sl[f][r] * (1.0f / 256.0f);
                    float e = __expf(fabsf(sv));
                    l[f] += e;                       // cross-lane reduce deferred
                    pk[r] = (_Float16)__builtin_copysignf(e, sv);
                }
                *reinterpret_cast<half4v*>(&PW[elw + f * 512]) = pk;
            }
        }

        // ---- PV: O[q][d] += P[q][key] * V[key][d]  (vb shared by both frags)
        __builtin_amdgcn_s_setprio(1);
        {
            int pel = q15 * 32 + ((g ^ ((q15 >> 1) & 3)) * 8);
            half8 pa0 = *reinterpret_cast<const half8*>(&PW[pel]);
            half8 pa1 = *reinterpret_cast<const half8*>(&PW[pel + 512]);
#pragma unroll
            for (int nt = 0; nt < 4; ++nt) {
                int d = nt * 16 + q15;
                int vel = d * 32 + ((g ^ ((d >> 1) & 3)) * 8);
                half8 vb = *reinterpret_cast<const half8*>(&VT[vel]);
                o[0][nt] = MFMA16(pa0, vb, o[0][nt]);
                o[1][nt] = MFMA16(pa1, vb, o[1][nt]);
            }
        }
        __builtin_amdgcn_s_setprio(0);
    };

    ISSUE(0, 0);
    ISSUE(1, 1);

#pragma unroll 1
    for (int base = 0; base < 30; base += 3) {
        asm volatile("s_waitcnt vmcnt(3)" ::: "memory");
        __builtin_amdgcn_s_barrier();
        COMPUTE(KhiS[0], KloS[0], VTS[0]);
        ISSUE(base + 2, 2);

        asm volatile("s_waitcnt vmcnt(3)" ::: "memory");
        __builtin_amdgcn_s_barrier();
        COMPUTE(KhiS[1], KloS[1], VTS[1]);
        ISSUE(base + 3, 0);

        asm volatile("s_waitcnt vmcnt(3)" ::: "memory");
        __builtin_amdgcn_s_barrier();
        COMPUTE(KhiS[2], KloS[2], VTS[2]);
        if (base + 4 < 32) ISSUE(base + 4, 1);
    }
    // kt = 30 (buf 0), kt = 31 (buf 1)
    asm volatile("s_waitcnt vmcnt(3)" ::: "memory");
    __builtin_amdgcn_s_barrier();
    COMPUTE(KhiS[0], KloS[0], VTS[0]);
    asm volatile("s_waitcnt vmcnt(0)" ::: "memory");
    __builtin_amdgcn_s_barrier();
    COMPUTE(KhiS[1], KloS[1], VTS[1]);
#undef ISSUE

    // ---- epilogue: deferred l reduction, then O[q][d] / l
#pragma unroll
    for (int f = 0; f < 2; ++f) {
        l[f] += __shfl_xor(l[f], 16);
        l[f] += __shfl_xor(l[f], 32);
    }
#pragma unroll
    for (int f = 0; f < 2; ++f) {
        float rl = 1.0f / l[f];
        float rlq[4];
#pragma unroll
        for (int r = 0; r < 4; ++r) rlq[r] = __shfl(rl, g * 4 + r);
#pragma unroll
        for (int nt = 0; nt < 4; ++nt)
#pragma unroll
            for (int r = 0; r < 4; ++r) {
                size_t row = (size_t)b * NN + qt * 128 + w * 32 + f * 16 + g * 4 + r;
                O[row * CC + h * 64 + nt * 16 + q15] = (_Float16)(o[f][nt][r] * rlq[r]);
            }
    }
}

// ---------------------------------------------------------------------------
extern "C" void kernel_launch(void* const* d_in, const int* in_sizes, int n_in,
                              void* d_out, int out_size, void* d_ws, size_t ws_size,
                              hipStream_t stream) {
    const float* x   = (const float*)d_in[0];
    const float* Wq  = (const float*)d_in[1];
    const float* bq  = (const float*)d_in[2];
    const float* Wk  = (const float*)d_in[3];
    const float* bk  = (const float*)d_in[4];
    const float* Wv  = (const float*)d_in[5];
    const float* bv  = (const float*)d_in[6];
    const float* srw = (const float*)d_in[7];
    const float* srb = (const float*)d_in[8];
    const float* lng = (const float*)d_in[9];
    const float* lnb = (const float*)d_in[10];
    const float* Wp  = (const float*)d_in[11];
    const float* bp  = (const float*)d_in[12];
    float* out = (float*)d_out;

    // workspace layout (~43 MB)
    char* wsb = (char*)d_ws;
    _Float16* Qhi  = (_Float16*)wsb;                   // 12.58 MB
    _Float16* Qlo  = (_Float16*)(wsb + 12582912);      // 12.58 MB (also attn O)
    _Float16* XRhi = (_Float16*)(wsb + 25165824);      // 3.15 MB
    _Float16* XRlo = (_Float16*)(wsb + 28311552);      // 3.15 MB
    _Float16* Khi  = (_Float16*)(wsb + 31457280);      // 3.15 MB
    _Float16* Klo  = (_Float16*)(wsb + 34603008);      // 3.15 MB
    _Float16* Vt   = (_Float16*)(wsb + 37748736);      // 3.15 MB [b][c][nk]
    _Float16* Wqh  = (_Float16*)(wsb + 40894464);      // 7 x 0.295 MB
    _Float16* Wql  = Wqh + 147456;
    _Float16* Wkh  = Wql + 147456;
    _Float16* Wkl  = Wkh + 147456;
    _Float16* Wvh  = Wkl + 147456;
    _Float16* Wvl  = Wvh + 147456;
    _Float16* Wph  = Wvl + 147456;
    _Float16* Ob   = Qlo;

    // 1) conv + LN -> pre-split pair, fused with weight pre-split
    srconv_splitw<<<dim3(BB * NKK + 1152), dim3(128), 0, stream>>>(
        x, srw, srb, lng, lnb, XRhi, XRlo,
        Wq, Wk, Wv, Wp, Wqh, Wql, Wkh, Wkl, Wvh, Wvl, Wph);
    // 2) fused Q + K + V projections (one launch, 1152 blocks)
    proj_all<<<dim3(1152), 256, 0, stream>>>(
        x, XRhi, XRlo, Wqh, Wql, Wkh, Wkl, Wvh, Wvl,
        bq, bk, bv, Qhi, Qlo, Khi, Klo, Vt);
    // 3) fused attention (128 q rows per block, 4 waves x 32 rows, 3 blocks/CU)
    attn_mfma<<<dim3(32, 6, 4), 256, 0, stream>>>(Qhi, Qlo, Khi, Klo, Vt, Ob);
    // 4) output projection -> d_out (f32)
    gemm_out<<<dim3(128, 6), 256, 0, stream>>>(Ob, Wph, bp, out);
}